// Round 15
// baseline (146.605 us; speedup 1.0000x reference)
//
#include <hip/hip_runtime.h>
#include <hip/hip_bf16.h>
#include <math.h>

// VQ-VAE VectorQuantizer: B=32,T=2048,D=64,K=1024 -> N=65536 rows.
// Round 15: top-2 candidate tracking (R13 = 98.7us, absmax 0.0; R14 reverted).
//  - fused (R13 body): track (m1,j1),(m2,j2),m3 per row. Certificate ladder:
//      m2 > m1+EPSB        -> j1 certified exact argmin (unchanged rule)
//      m3 > m1+EPSB        -> true argmin in {j1,j2}: exact 2-code rescore
//      else                -> full exact scan (rare)
//    Soundness: exact D(j) = d'(j)+sx+err, |err|<=delta~1.05e-5; EPSB=4e-5
//    >= 2*delta -> any j outside the band has D(j) strictly > D(j1),D(j2).
//    Equal-d' ties force m2<=m1+EPSB -> never certified/2-rescored wrongly.
//  - vq_rescore2: bit-exact R1 chains for {j1,j2}, u64 (dist,j) min. ~2us.
//  - vq_exact (R13-frozen) now handles only >=3-in-band rows.
//  - scalars folded into finalize (done-counter). prep slim (grid 32).

typedef __attribute__((ext_vector_type(8))) short bf16x8;
typedef __attribute__((ext_vector_type(4))) float f32x4;
typedef unsigned long long u64;

namespace {
constexpr int NROWS  = 65536;
constexpr int DDIM   = 64;
constexpr int KCODES = 1024;
constexpr float EPSB = 4e-5f;   // band; bound 2*delta ~ 2.1e-5

// ws layout (bytes) — ~7.1 MB
constexpr size_t WS_LOSS  = 0;                             // double
constexpr size_t WS_CNT   = 64;                            // int (full scan)
constexpr size_t WS_CNT2  = 68;                            // int (rescore2)
constexpr size_t WS_DONE  = 72;                            // int (finalize)
constexpr size_t WS_SE    = 256;                           // float[1024]
constexpr size_t WS_EHB   = 8192;                          // 128 KB
constexpr size_t WS_ELB   = WS_EHB  + (size_t)65536 * 2;   // 128 KB
constexpr size_t WS_BIDX  = WS_ELB  + (size_t)65536 * 2;   // int[N]
constexpr size_t WS_LIST  = WS_BIDX + (size_t)NROWS * 4;   // int[N]
constexpr size_t WS_ROWS2 = WS_LIST + (size_t)NROWS * 4;   // int[N]
constexpr size_t WS_JJ2   = WS_ROWS2 + (size_t)NROWS * 4;  // int[N]
constexpr size_t WS_KEY   = WS_JJ2  + (size_t)NROWS * 4;   // u64[N]
constexpr size_t WS_KV1   = WS_KEY  + (size_t)NROWS * 8;   // u64[4][N]
constexpr size_t WS_KV2   = WS_KV1  + (size_t)4 * NROWS * 8;
constexpr size_t WS_F3    = WS_KV2  + (size_t)4 * NROWS * 8; // float[4][N]
}

__device__ inline short f2bf(float v) {
  __hip_bfloat16 h = __float2bfloat16(v);
  return *reinterpret_cast<short*>(&h);
}
__device__ inline float bf2f(short s) {
  __hip_bfloat16 h;
  *reinterpret_cast<short*>(&h) = s;
  return __bfloat162float(h);
}
__device__ inline f32x4 mfma16(bf16x8 a, bf16x8 b, f32x4 c) {
  return __builtin_amdgcn_mfma_f32_16x16x32_bf16(a, b, c, 0, 0, 0);
}
__device__ inline unsigned int fflip(unsigned int b) {
  return b ^ ((unsigned int)((int)b >> 31) | 0x80000000u);
}
__device__ inline float kval(u64 k) {   // inverse of fflip on key's high word
  unsigned u = (unsigned)(k >> 32);
  u ^= ((int)u < 0) ? 0x80000000u : 0xFFFFFFFFu;
  return __uint_as_float(u);
}

// merge two sorted triples (k=u64 keys of 1st/2nd, f=values of 1st/2nd/3rd)
struct Tri { u64 k1, k2; float f1, f2, f3; };
__device__ inline Tri tmerge(const Tri& A, const Tri& B) {
  const bool aw = A.k1 <= B.k1;
  const u64  w2k = aw ? A.k2 : B.k2, l1k = aw ? B.k1 : A.k1;
  const float w2f = aw ? A.f2 : B.f2, l1f = aw ? B.f1 : A.f1;
  const float w3f = aw ? A.f3 : B.f3, l2f = aw ? B.f2 : A.f2;
  Tri r;
  r.k1 = aw ? A.k1 : B.k1;  r.f1 = aw ? A.f1 : B.f1;
  const bool s = w2k <= l1k;
  r.k2 = s ? w2k : l1k;     r.f2 = s ? w2f : l1f;
  r.f3 = fminf(fmaxf(w2f, l1f), fminf(w3f, l2f));
  return r;
}

// ---------------- prep: init accums, se (numpy pairwise), frag pack
__global__ __launch_bounds__(256) void vq_prep(const float* __restrict__ emb,
                                               float* __restrict__ se,
                                               short* __restrict__ ehB,
                                               short* __restrict__ elB,
                                               double* __restrict__ loss_accum,
                                               int* __restrict__ cnts) {
  #pragma clang fp contract(off)
  const int gid = blockIdx.x * 256 + (int)threadIdx.x;   // grid = 8192
  if (gid == 0) { *loss_accum = 0.0; cnts[0] = 0; cnts[1] = 0; cnts[2] = 0; }

  if (gid < KCODES) {   // se[j]: proven pairwise pattern
    const float* e = emb + (size_t)gid * DDIM;
    float r[8];
    #pragma unroll
    for (int j = 0; j < 8; ++j) r[j] = e[j] * e[j];
    #pragma unroll
    for (int i = 8; i < DDIM; i += 8) {
      #pragma unroll
      for (int j = 0; j < 8; ++j) r[j] += e[i + j] * e[i + j];
    }
    se[gid] = ((r[0] + r[1]) + (r[2] + r[3])) + ((r[4] + r[5]) + (r[6] + r[7]));
  }

  // pack frag (t,dc): lane l holds e[t*16+(l&15)][dc*32+(l>>4)*8 + i]  (R5-R14)
  {
    const int t  = gid >> 7;
    const int dc = (gid >> 6) & 1;
    const int l  = gid & 63;
    const int code = t * 16 + (l & 15);
    const int d0   = dc * 32 + (l >> 4) * 8;
    const float* ep = emb + (size_t)code * DDIM + d0;
    const size_t ob = ((size_t)(t * 2 + dc) * 64 + l) * 8;
    #pragma unroll
    for (int i = 0; i < 8; ++i) {
      const float v = ep[i];
      const short h = f2bf(v);
      ehB[ob + i] = h;
      elB[ob + i] = f2bf(v - bf2f(h));
    }
  }
}

// ---------------- fused sweep: block = 128 rows x 256 codes (R13 geometry),
// now tracking (m1,t1),(m2,t2),m3 per row.
__global__ __launch_bounds__(256, 2) void vq_fused(const float* __restrict__ x,
                                                   const short* __restrict__ ehB,
                                                   const short* __restrict__ elB,
                                                   const float* __restrict__ se,
                                                   u64* __restrict__ kv1,
                                                   u64* __restrict__ kv2,
                                                   float* __restrict__ f3v) {
  #pragma clang fp contract(off)
  __shared__ float sel[256];
  const int tid  = (int)threadIdx.x;
  const int l    = tid & 63;
  const int wid  = tid >> 6;
  const int quar = (int)blockIdx.x & 3;          // K-quarter: tiles [q*16, q*16+16)
  const int rblk = (int)blockIdx.x >> 2;
  const int t0   = quar * 16;
  sel[tid] = se[t0 * 16 + tid];
  __syncthreads();

  // A-fragments for 2 row-tiles (32 rows/wave)  [R13-frozen]
  const int wrb = rblk * 128 + wid * 32;
  bf16x8 xh[2][2], xl[2][2];
  #pragma unroll
  for (int rt = 0; rt < 2; ++rt) {
    const float* xp = x + (size_t)(wrb + rt * 16 + (l & 15)) * DDIM + (l >> 4) * 8;
    #pragma unroll
    for (int dc = 0; dc < 2; ++dc) {
      const float4 v0 = *reinterpret_cast<const float4*>(xp + dc * 32);
      const float4 v1 = *reinterpret_cast<const float4*>(xp + dc * 32 + 4);
      const float vv[8] = {v0.x, v0.y, v0.z, v0.w, v1.x, v1.y, v1.z, v1.w};
      #pragma unroll
      for (int i = 0; i < 8; ++i) {
        const short h = f2bf(vv[i]);
        xh[rt][dc][i] = h;
        xl[rt][dc][i] = f2bf(vv[i] - bf2f(h));
      }
    }
  }

  float m1v[2][4], m2v[2][4], m3v[2][4];
  int   m1t[2][4], m2t[2][4];
  #pragma unroll
  for (int rt = 0; rt < 2; ++rt)
    #pragma unroll
    for (int r = 0; r < 4; ++r) {
      m1v[rt][r] = INFINITY; m2v[rt][r] = INFINITY; m3v[rt][r] = INFINITY;
      m1t[rt][r] = 0; m2t[rt][r] = 0;
    }

  const size_t lb = (size_t)l * 8;
#define FRAGLD(buf, tt, half2) \
  (*reinterpret_cast<const bf16x8*>((buf) + (size_t)(tt) * 1024 + (half2) * 512 + lb))

  // 2-deep pipeline (R13-frozen schedule)
  bf16x8 c0 = FRAGLD(ehB, t0, 0), c1 = FRAGLD(ehB, t0, 1),
         c2 = FRAGLD(elB, t0, 0), c3 = FRAGLD(elB, t0, 1);
  bf16x8 n0 = FRAGLD(ehB, t0 + 1, 0), n1 = FRAGLD(ehB, t0 + 1, 1),
         n2 = FRAGLD(elB, t0 + 1, 0), n3 = FRAGLD(elB, t0 + 1, 1);

  const f32x4 kz = {0.f, 0.f, 0.f, 0.f};
  #pragma unroll 4
  for (int tt = 0; tt < 16; ++tt) {
    const int t = t0 + tt;
    const int tf = (tt + 2 < 16) ? t + 2 : t0 + 15;
    bf16x8 f0 = FRAGLD(ehB, tf, 0), f1 = FRAGLD(ehB, tf, 1),
           f2 = FRAGLD(elB, tf, 0), f3 = FRAGLD(elB, tf, 1);

    f32x4 a0, a1;
    a0 = mfma16(xh[0][0], c0, kz);  a1 = mfma16(xh[1][0], c0, kz);
    a0 = mfma16(xh[0][1], c1, a0);  a1 = mfma16(xh[1][1], c1, a1);
    a0 = mfma16(xh[0][0], c2, a0);  a1 = mfma16(xh[1][0], c2, a1);
    a0 = mfma16(xh[0][1], c3, a0);  a1 = mfma16(xh[1][1], c3, a1);
    a0 = mfma16(xl[0][0], c0, a0);  a1 = mfma16(xl[1][0], c0, a1);
    a0 = mfma16(xl[0][1], c1, a0);  a1 = mfma16(xl[1][1], c1, a1);

    const float sev = sel[tt * 16 + (l & 15)];
    #pragma unroll
    for (int r = 0; r < 4; ++r) {
      {
        const float d = __builtin_fmaf(-2.0f, a0[r], sev);   // d' = se - 2*dot
        const bool lt1 = d < m1v[0][r];
        const bool lt2 = d < m2v[0][r];
        m3v[0][r] = __builtin_amdgcn_fmed3f(m2v[0][r], m3v[0][r], d); // new 3rd
        m2t[0][r] = lt1 ? m1t[0][r] : (lt2 ? t : m2t[0][r]);
        m2v[0][r] = __builtin_amdgcn_fmed3f(m1v[0][r], m2v[0][r], d); // new 2nd
        m1t[0][r] = lt1 ? t : m1t[0][r];
        m1v[0][r] = fminf(m1v[0][r], d);
      }
      {
        const float d = __builtin_fmaf(-2.0f, a1[r], sev);
        const bool lt1 = d < m1v[1][r];
        const bool lt2 = d < m2v[1][r];
        m3v[1][r] = __builtin_amdgcn_fmed3f(m2v[1][r], m3v[1][r], d);
        m2t[1][r] = lt1 ? m1t[1][r] : (lt2 ? t : m2t[1][r]);
        m2v[1][r] = __builtin_amdgcn_fmed3f(m1v[1][r], m2v[1][r], d);
        m1t[1][r] = lt1 ? t : m1t[1][r];
        m1v[1][r] = fminf(m1v[1][r], d);
      }
    }
    c0 = n0; c1 = n1; c2 = n2; c3 = n3;
    n0 = f0; n1 = f1; n2 = f2; n3 = f3;
  }
#undef FRAGLD

  // 16-lane sorted-triple tournament; emit per-quarter (k1,k2,f3)
  const int colbase = l & 15;
  #pragma unroll
  for (int rt = 0; rt < 2; ++rt) {
    #pragma unroll
    for (int r = 0; r < 4; ++r) {
      Tri T;
      T.k1 = ((u64)fflip(__float_as_uint(m1v[rt][r])) << 32)
             | (unsigned)(m1t[rt][r] * 16 + colbase);
      T.k2 = ((u64)fflip(__float_as_uint(m2v[rt][r])) << 32)
             | (unsigned)(m2t[rt][r] * 16 + colbase);
      T.f1 = m1v[rt][r]; T.f2 = m2v[rt][r]; T.f3 = m3v[rt][r];
      #pragma unroll
      for (int off = 1; off < 16; off <<= 1) {
        Tri O;
        O.k1 = __shfl_xor(T.k1, off, 16);
        O.k2 = __shfl_xor(T.k2, off, 16);
        O.f1 = __shfl_xor(T.f1, off, 16);
        O.f2 = __shfl_xor(T.f2, off, 16);
        O.f3 = __shfl_xor(T.f3, off, 16);
        T = tmerge(T, O);
      }
      if (colbase == 0) {
        const int row = wrb + rt * 16 + (l >> 4) * 4 + r;
        kv1[(size_t)quar * NROWS + row] = T.k1;
        kv2[(size_t)quar * NROWS + row] = T.k2;
        f3v[(size_t)quar * NROWS + row] = T.f3;
      }
    }
  }
}

// ---------------- combine 4 quarters: certificate ladder + two compactions
__global__ __launch_bounds__(256) void vq_combine(const u64* __restrict__ kv1,
                                                  const u64* __restrict__ kv2,
                                                  const float* __restrict__ f3v,
                                                  int* __restrict__ bidx,
                                                  int* __restrict__ list,
                                                  int* __restrict__ rows2,
                                                  int* __restrict__ jj2,
                                                  int* __restrict__ cnts,
                                                  u64* __restrict__ keyBest) {
  const int gid = blockIdx.x * 256 + (int)threadIdx.x;
  const int l = (int)threadIdx.x & 63;
  keyBest[gid] = ~0ull;

  Tri Q[4];
  #pragma unroll
  for (int q = 0; q < 4; ++q) {
    Q[q].k1 = kv1[(size_t)q * NROWS + gid];
    Q[q].k2 = kv2[(size_t)q * NROWS + gid];
    Q[q].f1 = kval(Q[q].k1);
    Q[q].f2 = kval(Q[q].k2);
    Q[q].f3 = f3v[(size_t)q * NROWS + gid];
  }
  const Tri Z = tmerge(tmerge(Q[0], Q[1]), tmerge(Q[2], Q[3]));

  const bool cert  = Z.f2 > Z.f1 + EPSB;            // unique winner
  const bool two   = !cert && (Z.f3 > Z.f1 + EPSB); // winner in {j1,j2}
  const bool full  = !cert && !two;

  bidx[gid] = cert ? (int)(Z.k1 & 0xffffffffull) : -1;

  {  // compaction: rescore2 list
    const u64 mask = __ballot(two);
    int base = 0;
    if (l == 0 && mask) base = atomicAdd(&cnts[1], (int)__popcll(mask));
    base = __shfl(base, 0, 64);
    if (two) {
      const int off = (int)__popcll(mask & ((1ull << l) - 1ull));
      rows2[base + off] = gid;
      jj2[base + off] = ((int)(Z.k1 & 0xffffull) << 16) | (int)(Z.k2 & 0xffffull);
    }
  }
  {  // compaction: full-scan list
    const u64 mask = __ballot(full);
    int base = 0;
    if (l == 0 && mask) base = atomicAdd(&cnts[0], (int)__popcll(mask));
    base = __shfl(base, 0, 64);
    if (full) {
      const int off = (int)__popcll(mask & ((1ull << l) - 1ull));
      list[base + off] = gid;
    }
  }
}

// ---------------- rescore2: exact R1 chains for the two candidates
__global__ __launch_bounds__(256) void vq_rescore2(const float* __restrict__ x,
                                                   const float* __restrict__ emb,
                                                   const float* __restrict__ se,
                                                   const int* __restrict__ rows2,
                                                   const int* __restrict__ jj2,
                                                   const int* __restrict__ cnts,
                                                   int* __restrict__ bidx) {
  #pragma clang fp contract(off)
  const int n2 = cnts[1];
  for (int idx = blockIdx.x * 256 + (int)threadIdx.x; idx < n2;
       idx += (int)gridDim.x * 256) {
    const int row = rows2[idx];
    const int jj  = jj2[idx];
    const int j1  = jj >> 16;
    const int j2  = jj & 0xffff;
    const float4* xr4 = reinterpret_cast<const float4*>(x + (size_t)row * DDIM);
    const float4* e14 = reinterpret_cast<const float4*>(emb + (size_t)j1 * DDIM);
    const float4* e24 = reinterpret_cast<const float4*>(emb + (size_t)j2 * DDIM);

    // sx: numpy pairwise 8-accumulator (proven R3/R8 float4-streaming form)
    float rr[8];
    {
      const float4 a = xr4[0], b = xr4[1];
      rr[0] = a.x * a.x; rr[1] = a.y * a.y; rr[2] = a.z * a.z; rr[3] = a.w * a.w;
      rr[4] = b.x * b.x; rr[5] = b.y * b.y; rr[6] = b.z * b.z; rr[7] = b.w * b.w;
    }
    #pragma unroll
    for (int i = 2; i < 16; i += 2) {
      const float4 a = xr4[i], b = xr4[i + 1];
      rr[0] += a.x * a.x; rr[1] += a.y * a.y; rr[2] += a.z * a.z; rr[3] += a.w * a.w;
      rr[4] += b.x * b.x; rr[5] += b.y * b.y; rr[6] += b.z * b.z; rr[7] += b.w * b.w;
    }
    const float sx = ((rr[0] + rr[1]) + (rr[2] + rr[3])) + ((rr[4] + rr[5]) + (rr[6] + rr[7]));

    // two sequential d=0..63 fmaf chains (bit-exact R1 order)
    float a1 = 0.f, a2 = 0.f;
    #pragma unroll
    for (int q = 0; q < 16; ++q) {
      const float4 xv = xr4[q];
      const float4 v1 = e14[q];
      const float4 v2 = e24[q];
      a1 = __builtin_fmaf(xv.x, v1.x, a1); a1 = __builtin_fmaf(xv.y, v1.y, a1);
      a1 = __builtin_fmaf(xv.z, v1.z, a1); a1 = __builtin_fmaf(xv.w, v1.w, a1);
      a2 = __builtin_fmaf(xv.x, v2.x, a2); a2 = __builtin_fmaf(xv.y, v2.y, a2);
      a2 = __builtin_fmaf(xv.z, v2.z, a2); a2 = __builtin_fmaf(xv.w, v2.w, a2);
    }
    const float T1 = sx + se[j1];                      // fl(sx + se_j)
    const float T2 = sx + se[j2];
    const float D1 = __builtin_fmaf(-2.0f, a1, T1);    // fl(T - 2*acc)
    const float D2 = __builtin_fmaf(-2.0f, a2, T2);
    const u64 k1 = ((u64)fflip(__float_as_uint(D1)) << 32) | (unsigned)j1;
    const u64 k2 = ((u64)fflip(__float_as_uint(D2)) << 32) | (unsigned)j2;
    bidx[row] = (int)(((k1 < k2) ? k1 : k2) & 0xffffffffull);  // first-min
  }
}

// ---------------- exact full scan (R13-frozen): 1-wave blocks, 32-code parts
__global__ __launch_bounds__(64) void vq_exact(const float* __restrict__ x,
                                               const float* __restrict__ emb,
                                               const float* __restrict__ se,
                                               const int* __restrict__ list,
                                               const int* __restrict__ cnts,
                                               u64* __restrict__ keyBest) {
  #pragma clang fp contract(off)
  __shared__ __align__(16) float eL[32 * DDIM];
  const int n = cnts[0];
  if (n == 0) return;
  const int nrb = (n + 63) >> 6;
  const int ntasks = nrb * 32;
  const int l = (int)threadIdx.x;

  for (int t = (int)blockIdx.x; t < ntasks; t += (int)gridDim.x) {
    const int part = t & 31;
    const int rb   = t >> 5;
    const int j0   = part * 32;

    {
      const float4* src = reinterpret_cast<const float4*>(emb + (size_t)j0 * DDIM);
      float4* dst = reinterpret_cast<float4*>(eL);
      #pragma unroll
      for (int i = 0; i < 8; ++i) dst[i * 64 + l] = src[i * 64 + l];
    }
    __syncthreads();

    const int idx = rb * 64 + l;
    const bool act = idx < n;
    const int row = act ? list[idx] : 0;
    const float4* xr4 = reinterpret_cast<const float4*>(x + (size_t)row * DDIM);

    float xv[DDIM];
    #pragma unroll
    for (int q = 0; q < 16; ++q) {
      const float4 v = xr4[q];
      xv[q * 4 + 0] = v.x; xv[q * 4 + 1] = v.y;
      xv[q * 4 + 2] = v.z; xv[q * 4 + 3] = v.w;
    }

    float rr[8];
    #pragma unroll
    for (int j = 0; j < 8; ++j) rr[j] = xv[j] * xv[j];
    #pragma unroll
    for (int i = 8; i < DDIM; i += 8) {
      #pragma unroll
      for (int j = 0; j < 8; ++j) rr[j] += xv[i + j] * xv[i + j];
    }
    const float sx = ((rr[0] + rr[1]) + (rr[2] + rr[3])) + ((rr[4] + rr[5]) + (rr[6] + rr[7]));

    u64 best = ~0ull;
    #pragma unroll 1
    for (int g = 0; g < 8; ++g) {
      const int jb = g * 4;
      const float4* e0 = reinterpret_cast<const float4*>(eL + (jb + 0) * DDIM);
      const float4* e1 = reinterpret_cast<const float4*>(eL + (jb + 1) * DDIM);
      const float4* e2 = reinterpret_cast<const float4*>(eL + (jb + 2) * DDIM);
      const float4* e3 = reinterpret_cast<const float4*>(eL + (jb + 3) * DDIM);
      float a0 = 0.f, a1 = 0.f, a2 = 0.f, a3 = 0.f;
      #pragma unroll
      for (int q = 0; q < 16; ++q) {
        const float4 v0 = e0[q], v1 = e1[q], v2 = e2[q], v3 = e3[q];
        const float xa = xv[q * 4 + 0], xb = xv[q * 4 + 1];
        const float xc = xv[q * 4 + 2], xd = xv[q * 4 + 3];
        a0 = __builtin_fmaf(xa, v0.x, a0); a0 = __builtin_fmaf(xb, v0.y, a0);
        a0 = __builtin_fmaf(xc, v0.z, a0); a0 = __builtin_fmaf(xd, v0.w, a0);
        a1 = __builtin_fmaf(xa, v1.x, a1); a1 = __builtin_fmaf(xb, v1.y, a1);
        a1 = __builtin_fmaf(xc, v1.z, a1); a1 = __builtin_fmaf(xd, v1.w, a1);
        a2 = __builtin_fmaf(xa, v2.x, a2); a2 = __builtin_fmaf(xb, v2.y, a2);
        a2 = __builtin_fmaf(xc, v2.z, a2); a2 = __builtin_fmaf(xd, v2.w, a2);
        a3 = __builtin_fmaf(xa, v3.x, a3); a3 = __builtin_fmaf(xb, v3.y, a3);
        a3 = __builtin_fmaf(xc, v3.z, a3); a3 = __builtin_fmaf(xd, v3.w, a3);
      }
      const int j = j0 + jb;
      const float T0 = sx + se[j + 0];
      const float T1 = sx + se[j + 1];
      const float T2 = sx + se[j + 2];
      const float T3 = sx + se[j + 3];
      const float di0 = __builtin_fmaf(-2.0f, a0, T0);
      const float di1 = __builtin_fmaf(-2.0f, a1, T1);
      const float di2 = __builtin_fmaf(-2.0f, a2, T2);
      const float di3 = __builtin_fmaf(-2.0f, a3, T3);
      u64 k;
      k = ((u64)fflip(__float_as_uint(di0)) << 32) | (unsigned)(j + 0);
      best = (k < best) ? k : best;
      k = ((u64)fflip(__float_as_uint(di1)) << 32) | (unsigned)(j + 1);
      best = (k < best) ? k : best;
      k = ((u64)fflip(__float_as_uint(di2)) << 32) | (unsigned)(j + 2);
      best = (k < best) ? k : best;
      k = ((u64)fflip(__float_as_uint(di3)) << 32) | (unsigned)(j + 3);
      best = (k < best) ? k : best;
    }
    if (act) atomicMin(&keyBest[row], best);
    __syncthreads();
  }
}

// ---------------- finalize (+ scalars via done-counter)
__global__ __launch_bounds__(256) void vq_finalize(const float* __restrict__ x,
                                                   const float* __restrict__ emb,
                                                   const int* __restrict__ bidx,
                                                   const u64* __restrict__ keyBest,
                                                   float* __restrict__ out,
                                                   double* __restrict__ loss_accum,
                                                   int* __restrict__ done) {
  #pragma clang fp contract(off)
  __shared__ float wsum[4];
  const int tid = (int)threadIdx.x;
  const int l   = tid & 63;
  const int wid = tid >> 6;
  const int sub = l >> 4;
  const int q16 = l & 15;
  float lacc = 0.f;

  #pragma unroll
  for (int it = 0; it < 4; ++it) {   // block covers 64 rows
    const int row = blockIdx.x * 64 + it * 16 + wid * 4 + sub;
    int bi = bidx[row];
    if (bi < 0) bi = (int)(keyBest[row] & 0xffffffffull);
    const float4 xv = reinterpret_cast<const float4*>(x)[(size_t)row * 16 + q16];
    const float4 ev = reinterpret_cast<const float4*>(emb)[(size_t)bi * 16 + q16];
    const float da = ev.x - xv.x;
    const float db = ev.y - xv.y;
    const float dc = ev.z - xv.z;
    const float dd = ev.w - xv.w;
    float4 o;
    o.x = xv.x + da; o.y = xv.y + db; o.z = xv.z + dc; o.w = xv.w + dd;
    reinterpret_cast<float4*>(out)[(size_t)row * 16 + q16] = o;
    lacc += da * da + db * db + dc * dc + dd * dd;
    if (q16 == 0) out[(size_t)NROWS * DDIM + row] = (float)bi;
  }
  #pragma unroll
  for (int off = 32; off > 0; off >>= 1) lacc += __shfl_down(lacc, off, 64);
  if (l == 0) wsum[wid] = lacc;
  __syncthreads();
  if (tid == 0) {
    atomicAdd(loss_accum, (double)(wsum[0] + wsum[1] + wsum[2] + wsum[3]));
    __threadfence();
    if (atomicAdd(done, 1) == (int)gridDim.x - 1) {   // last block: scalars
      __threadfence();
      const double mm = *loss_accum / (double)((size_t)NROWS * DDIM);
      const float el = (float)mm;
      float* tail = out + (size_t)NROWS * DDIM + NROWS;
      tail[0] = 0.25f * el;
      tail[1] = el;
      tail[2] = 0.0f;
    }
  }
}

// ============================================================================
extern "C" void kernel_launch(void* const* d_in, const int* in_sizes, int n_in,
                              void* d_out, int out_size, void* d_ws, size_t ws_size,
                              hipStream_t stream) {
  const float* x   = (const float*)d_in[0];  // [N, 64]
  const float* emb = (const float*)d_in[1];  // [K, 64]
  float* out = (float*)d_out;
  char* ws = (char*)d_ws;

  double* loss_accum = (double*)(ws + WS_LOSS);
  int*    cnts       = (int*)(ws + WS_CNT);    // [0]=full, [1]=rescore2, [2]=done
  int*    done       = (int*)(ws + WS_DONE);
  float*  se         = (float*)(ws + WS_SE);
  short*  ehB        = (short*)(ws + WS_EHB);
  short*  elB        = (short*)(ws + WS_ELB);
  int*    bidx       = (int*)(ws + WS_BIDX);
  int*    list       = (int*)(ws + WS_LIST);
  int*    rows2      = (int*)(ws + WS_ROWS2);
  int*    jj2        = (int*)(ws + WS_JJ2);
  u64*    keyBest    = (u64*)(ws + WS_KEY);
  u64*    kv1        = (u64*)(ws + WS_KV1);
  u64*    kv2        = (u64*)(ws + WS_KV2);
  float*  f3v        = (float*)(ws + WS_F3);

  vq_prep<<<32, 256, 0, stream>>>(emb, se, ehB, elB, loss_accum, cnts);
  vq_fused<<<(NROWS / 128) * 4, 256, 0, stream>>>(x, ehB, elB, se, kv1, kv2, f3v);
  vq_combine<<<NROWS / 256, 256, 0, stream>>>(kv1, kv2, f3v, bidx, list,
                                              rows2, jj2, cnts, keyBest);
  vq_rescore2<<<256, 256, 0, stream>>>(x, emb, se, rows2, jj2, cnts, bidx);
  vq_exact<<<2048, 64, 0, stream>>>(x, emb, se, list, cnts, keyBest);
  vq_finalize<<<NROWS / 64, 256, 0, stream>>>(x, emb, bidx, keyBest, out,
                                              loss_accum, done);
}

// Round 16
// 113.207 us; speedup vs baseline: 1.2950x; 1.2950x over previous
//
#include <hip/hip_runtime.h>
#include <hip/hip_bf16.h>
#include <math.h>

// VQ-VAE VectorQuantizer: B=32,T=2048,D=64,K=1024 -> N=65536 rows.
// Round 16: revert to R13 (98.7us best, absmax 0.0) + three de-risked deltas:
//  - fused chain-split: 6-deep MFMA accum chain -> 2x 3-deep (half0/half1),
//    summed with one v_add before the fmaf. Dep-distance 2->4 halves the
//    per-tile MFMA latency path (fused is dependency-bound: time invariant
//    to occupancy 20->33%, ~8x above issue floor). Estimate rounding shifts
//    ~1e-6, absorbed by EPSB margin (bound ~1.05e-5 << 4e-5); rescore exact.
//  - med3 m2-update (R14-component, absmax 0.0 there; regression was VGPR).
//  - slim prep (grid 32; keyBest init in combine, R14-proven) + scalars
//    folded into finalize via done-counter (R15-proven). 5 launches total.
// Certificate math, combine tournament, exact scan, finalize: R13-frozen.

typedef __attribute__((ext_vector_type(8))) short bf16x8;
typedef __attribute__((ext_vector_type(4))) float f32x4;
typedef unsigned long long u64;

namespace {
constexpr int NROWS  = 65536;
constexpr int DDIM   = 64;
constexpr int KCODES = 1024;
constexpr float EPSB = 4e-5f;   // certificate band; bound ~1.05e-5 (+1e-6 split)

// ws layout (bytes) — ~7.6 MB
constexpr size_t WS_LOSS = 0;                            // double
constexpr size_t WS_CNT  = 64;                           // int[2]: full, done
constexpr size_t WS_SE   = 256;                          // float[1024]
constexpr size_t WS_EHB  = 8192;                         // bf16 frags 128 KB
constexpr size_t WS_ELB  = WS_EHB + (size_t)65536 * 2;   // 128 KB
constexpr size_t WS_BIDX = WS_ELB + (size_t)65536 * 2;   // int[N]
constexpr size_t WS_LIST = WS_BIDX + (size_t)NROWS * 4;  // int[N]
constexpr size_t WS_KEY  = WS_LIST + (size_t)NROWS * 4;  // u64[N]
constexpr size_t WS_MV   = WS_KEY + (size_t)NROWS * 8;   // float2[4][N]
constexpr size_t WS_KV   = WS_MV + (size_t)4 * NROWS * 8; // u64[4][N]
}

__device__ inline short f2bf(float v) {
  __hip_bfloat16 h = __float2bfloat16(v);
  return *reinterpret_cast<short*>(&h);
}
__device__ inline float bf2f(short s) {
  __hip_bfloat16 h;
  *reinterpret_cast<short*>(&h) = s;
  return __bfloat162float(h);
}
__device__ inline f32x4 mfma16(bf16x8 a, bf16x8 b, f32x4 c) {
  return __builtin_amdgcn_mfma_f32_16x16x32_bf16(a, b, c, 0, 0, 0);
}
__device__ inline unsigned int fflip(unsigned int b) {
  return b ^ ((unsigned int)((int)b >> 31) | 0x80000000u);
}

// ---------------- prep: init accums, se (numpy pairwise), frag pack (grid 32)
__global__ __launch_bounds__(256) void vq_prep(const float* __restrict__ emb,
                                               float* __restrict__ se,
                                               short* __restrict__ ehB,
                                               short* __restrict__ elB,
                                               double* __restrict__ loss_accum,
                                               int* __restrict__ cnts) {
  #pragma clang fp contract(off)
  const int gid = blockIdx.x * 256 + (int)threadIdx.x;   // grid = 8192
  if (gid == 0) { *loss_accum = 0.0; cnts[0] = 0; cnts[1] = 0; }

  if (gid < KCODES) {   // se[j]: proven pairwise pattern
    const float* e = emb + (size_t)gid * DDIM;
    float r[8];
    #pragma unroll
    for (int j = 0; j < 8; ++j) r[j] = e[j] * e[j];
    #pragma unroll
    for (int i = 8; i < DDIM; i += 8) {
      #pragma unroll
      for (int j = 0; j < 8; ++j) r[j] += e[i + j] * e[i + j];
    }
    se[gid] = ((r[0] + r[1]) + (r[2] + r[3])) + ((r[4] + r[5]) + (r[6] + r[7]));
  }

  // pack frag (t,dc): lane l holds e[t*16+(l&15)][dc*32+(l>>4)*8 + i]  (R5-R15)
  {
    const int t  = gid >> 7;
    const int dc = (gid >> 6) & 1;
    const int l  = gid & 63;
    const int code = t * 16 + (l & 15);
    const int d0   = dc * 32 + (l >> 4) * 8;
    const float* ep = emb + (size_t)code * DDIM + d0;
    const size_t ob = ((size_t)(t * 2 + dc) * 64 + l) * 8;
    #pragma unroll
    for (int i = 0; i < 8; ++i) {
      const float v = ep[i];
      const short h = f2bf(v);
      ehB[ob + i] = h;
      elB[ob + i] = f2bf(v - bf2f(h));
    }
  }
}

// ---------------- fused sweep: block = 128 rows x 256 codes (R13 geometry),
// split accumulator chains (dep-distance 4), med3 m2-update.
__global__ __launch_bounds__(256, 2) void vq_fused(const float* __restrict__ x,
                                                   const short* __restrict__ ehB,
                                                   const short* __restrict__ elB,
                                                   const float* __restrict__ se,
                                                   float2* __restrict__ mv,
                                                   u64* __restrict__ kv) {
  #pragma clang fp contract(off)
  __shared__ float sel[256];
  const int tid  = (int)threadIdx.x;
  const int l    = tid & 63;
  const int wid  = tid >> 6;
  const int quar = (int)blockIdx.x & 3;          // K-quarter: tiles [q*16, q*16+16)
  const int rblk = (int)blockIdx.x >> 2;
  const int t0   = quar * 16;
  sel[tid] = se[t0 * 16 + tid];
  __syncthreads();

  // A-fragments for 2 row-tiles (32 rows/wave)  [R13-frozen]
  const int wrb = rblk * 128 + wid * 32;
  bf16x8 xh[2][2], xl[2][2];
  #pragma unroll
  for (int rt = 0; rt < 2; ++rt) {
    const float* xp = x + (size_t)(wrb + rt * 16 + (l & 15)) * DDIM + (l >> 4) * 8;
    #pragma unroll
    for (int dc = 0; dc < 2; ++dc) {
      const float4 v0 = *reinterpret_cast<const float4*>(xp + dc * 32);
      const float4 v1 = *reinterpret_cast<const float4*>(xp + dc * 32 + 4);
      const float vv[8] = {v0.x, v0.y, v0.z, v0.w, v1.x, v1.y, v1.z, v1.w};
      #pragma unroll
      for (int i = 0; i < 8; ++i) {
        const short h = f2bf(vv[i]);
        xh[rt][dc][i] = h;
        xl[rt][dc][i] = f2bf(vv[i] - bf2f(h));
      }
    }
  }

  float m1v[2][4], m2v[2][4];
  int   m1t[2][4];
  #pragma unroll
  for (int rt = 0; rt < 2; ++rt)
    #pragma unroll
    for (int r = 0; r < 4; ++r) { m1v[rt][r] = INFINITY; m2v[rt][r] = INFINITY; m1t[rt][r] = 0; }

  const size_t lb = (size_t)l * 8;
#define FRAGLD(buf, tt, half2) \
  (*reinterpret_cast<const bf16x8*>((buf) + (size_t)(tt) * 1024 + (half2) * 512 + lb))

  // 2-deep pipeline (R13-frozen schedule)
  bf16x8 c0 = FRAGLD(ehB, t0, 0), c1 = FRAGLD(ehB, t0, 1),
         c2 = FRAGLD(elB, t0, 0), c3 = FRAGLD(elB, t0, 1);
  bf16x8 n0 = FRAGLD(ehB, t0 + 1, 0), n1 = FRAGLD(ehB, t0 + 1, 1),
         n2 = FRAGLD(elB, t0 + 1, 0), n3 = FRAGLD(elB, t0 + 1, 1);

  const f32x4 kz = {0.f, 0.f, 0.f, 0.f};
  #pragma unroll 4
  for (int tt = 0; tt < 16; ++tt) {
    const int t = t0 + tt;
    const int tf = (tt + 2 < 16) ? t + 2 : t0 + 15;
    bf16x8 f0 = FRAGLD(ehB, tf, 0), f1 = FRAGLD(ehB, tf, 1),
           f2 = FRAGLD(elB, tf, 0), f3 = FRAGLD(elB, tf, 1);

    // split chains: a* = half0 (c0,c2), b* = half1 (c1,c3); dep-distance 4
    f32x4 a0, a1, b0, b1;
    a0 = mfma16(xh[0][0], c0, kz);  a1 = mfma16(xh[1][0], c0, kz);
    b0 = mfma16(xh[0][1], c1, kz);  b1 = mfma16(xh[1][1], c1, kz);
    a0 = mfma16(xh[0][0], c2, a0);  a1 = mfma16(xh[1][0], c2, a1);
    b0 = mfma16(xh[0][1], c3, b0);  b1 = mfma16(xh[1][1], c3, b1);
    a0 = mfma16(xl[0][0], c0, a0);  a1 = mfma16(xl[1][0], c0, a1);
    b0 = mfma16(xl[0][1], c1, b0);  b1 = mfma16(xl[1][1], c1, b1);

    const float sev = sel[tt * 16 + (l & 15)];
    #pragma unroll
    for (int r = 0; r < 4; ++r) {
      {
        const float s = a0[r] + b0[r];
        const float d = __builtin_fmaf(-2.0f, s, sev);       // d' = se - 2*dot
        m2v[0][r] = __builtin_amdgcn_fmed3f(m1v[0][r], m2v[0][r], d);
        m1t[0][r] = (d < m1v[0][r]) ? t : m1t[0][r];
        m1v[0][r] = fminf(m1v[0][r], d);
      }
      {
        const float s = a1[r] + b1[r];
        const float d = __builtin_fmaf(-2.0f, s, sev);
        m2v[1][r] = __builtin_amdgcn_fmed3f(m1v[1][r], m2v[1][r], d);
        m1t[1][r] = (d < m1v[1][r]) ? t : m1t[1][r];
        m1v[1][r] = fminf(m1v[1][r], d);
      }
    }
    c0 = n0; c1 = n1; c2 = n2; c3 = n3;
    n0 = f0; n1 = f1; n2 = f2; n3 = f3;
  }
#undef FRAGLD

  // 16-lane merge (R6-R13-proven); emit per-quarter partials
  const int colbase = l & 15;
  #pragma unroll
  for (int rt = 0; rt < 2; ++rt) {
    #pragma unroll
    for (int r = 0; r < 4; ++r) {
      float m1 = m1v[rt][r], m2 = m2v[rt][r];
      u64 key = ((u64)fflip(__float_as_uint(m1)) << 32)
                | (unsigned)(m1t[rt][r] * 16 + colbase);
      #pragma unroll
      for (int off = 1; off < 16; off <<= 1) {
        const u64 ok = __shfl_xor(key, off, 16);
        const float om1 = __shfl_xor(m1, off, 16);
        const float om2 = __shfl_xor(m2, off, 16);
        m2 = fminf(fminf(m2, om2), fmaxf(m1, om1));
        m1 = fminf(m1, om1);
        key = (ok < key) ? ok : key;
      }
      if (colbase == 0) {
        const int row = wrb + rt * 16 + (l >> 4) * 4 + r;
        mv[(size_t)quar * NROWS + row] = make_float2(m1, m2);
        kv[(size_t)quar * NROWS + row] = key;
      }
    }
  }
}

// ---------------- combine 4 quarters + certificate + compaction + keyBest init
__global__ __launch_bounds__(256) void vq_combine(const float2* __restrict__ mv,
                                                  const u64* __restrict__ kv,
                                                  int* __restrict__ bidx,
                                                  int* __restrict__ list,
                                                  int* __restrict__ cnts,
                                                  u64* __restrict__ keyBest) {
  const int gid = blockIdx.x * 256 + (int)threadIdx.x;
  const int l = (int)threadIdx.x & 63;
  keyBest[gid] = ~0ull;
  const float2 A = mv[gid];
  const float2 B = mv[(size_t)NROWS + gid];
  const float2 C = mv[(size_t)2 * NROWS + gid];
  const float2 D = mv[(size_t)3 * NROWS + gid];
  u64 kg = kv[gid];
  {
    u64 k2 = kv[(size_t)NROWS + gid];     kg = (k2 < kg) ? k2 : kg;
    k2 = kv[(size_t)2 * NROWS + gid];     kg = (k2 < kg) ? k2 : kg;
    k2 = kv[(size_t)3 * NROWS + gid];     kg = (k2 < kg) ? k2 : kg;
  }
  // union's two smallest over 4 disjoint quarters (exact tournament rule)
  const float lo1 = fminf(A.x, B.x), hi1 = fmaxf(A.x, B.x);
  const float lo2 = fminf(C.x, D.x), hi2 = fmaxf(C.x, D.x);
  const float m1g = fminf(lo1, lo2);
  const float sec = fminf(fmaxf(lo1, lo2), fminf(hi1, hi2));  // secondmin{m1}
  const float m2g = fminf(sec, fminf(fminf(A.y, B.y), fminf(C.y, D.y)));
  const bool cert = m2g > m1g + EPSB;
  bidx[gid] = cert ? (int)(kg & 0xffffffffull) : -1;

  const u64 mask = __ballot(!cert);
  int base = 0;
  if (l == 0 && mask) base = atomicAdd(&cnts[0], (int)__popcll(mask));
  base = __shfl(base, 0, 64);
  if (!cert) {
    const int off = (int)__popcll(mask & ((1ull << l) - 1ull));
    list[base + off] = gid;
  }
}

// ---------------- exact scan (R13-frozen): 1-wave blocks, 32-code LDS parts
__global__ __launch_bounds__(64) void vq_exact(const float* __restrict__ x,
                                               const float* __restrict__ emb,
                                               const float* __restrict__ se,
                                               const int* __restrict__ list,
                                               const int* __restrict__ cnts,
                                               u64* __restrict__ keyBest) {
  #pragma clang fp contract(off)
  __shared__ __align__(16) float eL[32 * DDIM];
  const int n = cnts[0];
  if (n == 0) return;
  const int nrb = (n + 63) >> 6;
  const int ntasks = nrb * 32;
  const int l = (int)threadIdx.x;

  for (int t = (int)blockIdx.x; t < ntasks; t += (int)gridDim.x) {
    const int part = t & 31;
    const int rb   = t >> 5;
    const int j0   = part * 32;

    {
      const float4* src = reinterpret_cast<const float4*>(emb + (size_t)j0 * DDIM);
      float4* dst = reinterpret_cast<float4*>(eL);
      #pragma unroll
      for (int i = 0; i < 8; ++i) dst[i * 64 + l] = src[i * 64 + l];
    }
    __syncthreads();

    const int idx = rb * 64 + l;
    const bool act = idx < n;
    const int row = act ? list[idx] : 0;
    const float4* xr4 = reinterpret_cast<const float4*>(x + (size_t)row * DDIM);

    float xv[DDIM];
    #pragma unroll
    for (int q = 0; q < 16; ++q) {
      const float4 v = xr4[q];
      xv[q * 4 + 0] = v.x; xv[q * 4 + 1] = v.y;
      xv[q * 4 + 2] = v.z; xv[q * 4 + 3] = v.w;
    }

    float rr[8];
    #pragma unroll
    for (int j = 0; j < 8; ++j) rr[j] = xv[j] * xv[j];
    #pragma unroll
    for (int i = 8; i < DDIM; i += 8) {
      #pragma unroll
      for (int j = 0; j < 8; ++j) rr[j] += xv[i + j] * xv[i + j];
    }
    const float sx = ((rr[0] + rr[1]) + (rr[2] + rr[3])) + ((rr[4] + rr[5]) + (rr[6] + rr[7]));

    u64 best = ~0ull;
    #pragma unroll 1
    for (int g = 0; g < 8; ++g) {
      const int jb = g * 4;
      const float4* e0 = reinterpret_cast<const float4*>(eL + (jb + 0) * DDIM);
      const float4* e1 = reinterpret_cast<const float4*>(eL + (jb + 1) * DDIM);
      const float4* e2 = reinterpret_cast<const float4*>(eL + (jb + 2) * DDIM);
      const float4* e3 = reinterpret_cast<const float4*>(eL + (jb + 3) * DDIM);
      float a0 = 0.f, a1 = 0.f, a2 = 0.f, a3 = 0.f;
      #pragma unroll
      for (int q = 0; q < 16; ++q) {   // per code: sequential d=0..63 (R1 chain)
        const float4 v0 = e0[q], v1 = e1[q], v2 = e2[q], v3 = e3[q];
        const float xa = xv[q * 4 + 0], xb = xv[q * 4 + 1];
        const float xc = xv[q * 4 + 2], xd = xv[q * 4 + 3];
        a0 = __builtin_fmaf(xa, v0.x, a0); a0 = __builtin_fmaf(xb, v0.y, a0);
        a0 = __builtin_fmaf(xc, v0.z, a0); a0 = __builtin_fmaf(xd, v0.w, a0);
        a1 = __builtin_fmaf(xa, v1.x, a1); a1 = __builtin_fmaf(xb, v1.y, a1);
        a1 = __builtin_fmaf(xc, v1.z, a1); a1 = __builtin_fmaf(xd, v1.w, a1);
        a2 = __builtin_fmaf(xa, v2.x, a2); a2 = __builtin_fmaf(xb, v2.y, a2);
        a2 = __builtin_fmaf(xc, v2.z, a2); a2 = __builtin_fmaf(xd, v2.w, a2);
        a3 = __builtin_fmaf(xa, v3.x, a3); a3 = __builtin_fmaf(xb, v3.y, a3);
        a3 = __builtin_fmaf(xc, v3.z, a3); a3 = __builtin_fmaf(xd, v3.w, a3);
      }
      const int j = j0 + jb;
      const float T0 = sx + se[j + 0];
      const float T1 = sx + se[j + 1];
      const float T2 = sx + se[j + 2];
      const float T3 = sx + se[j + 3];
      const float di0 = __builtin_fmaf(-2.0f, a0, T0);
      const float di1 = __builtin_fmaf(-2.0f, a1, T1);
      const float di2 = __builtin_fmaf(-2.0f, a2, T2);
      const float di3 = __builtin_fmaf(-2.0f, a3, T3);
      u64 k;
      k = ((u64)fflip(__float_as_uint(di0)) << 32) | (unsigned)(j + 0);
      best = (k < best) ? k : best;
      k = ((u64)fflip(__float_as_uint(di1)) << 32) | (unsigned)(j + 1);
      best = (k < best) ? k : best;
      k = ((u64)fflip(__float_as_uint(di2)) << 32) | (unsigned)(j + 2);
      best = (k < best) ? k : best;
      k = ((u64)fflip(__float_as_uint(di3)) << 32) | (unsigned)(j + 3);
      best = (k < best) ? k : best;
    }
    if (act) atomicMin(&keyBest[row], best);   // (dist asc, j asc) == first-min
    __syncthreads();
  }
}

// ---------------- finalize (+ scalars via done-counter, R15-proven)
__global__ __launch_bounds__(256) void vq_finalize(const float* __restrict__ x,
                                                   const float* __restrict__ emb,
                                                   const int* __restrict__ bidx,
                                                   const u64* __restrict__ keyBest,
                                                   float* __restrict__ out,
                                                   double* __restrict__ loss_accum,
                                                   int* __restrict__ cnts) {
  #pragma clang fp contract(off)
  __shared__ float wsum[4];
  const int tid = (int)threadIdx.x;
  const int l   = tid & 63;
  const int wid = tid >> 6;
  const int sub = l >> 4;
  const int q16 = l & 15;
  float lacc = 0.f;

  #pragma unroll
  for (int it = 0; it < 4; ++it) {   // block covers 64 rows
    const int row = blockIdx.x * 64 + it * 16 + wid * 4 + sub;
    int bi = bidx[row];
    if (bi < 0) bi = (int)(keyBest[row] & 0xffffffffull);
    const float4 xv = reinterpret_cast<const float4*>(x)[(size_t)row * 16 + q16];
    const float4 ev = reinterpret_cast<const float4*>(emb)[(size_t)bi * 16 + q16];
    const float da = ev.x - xv.x;
    const float db = ev.y - xv.y;
    const float dc = ev.z - xv.z;
    const float dd = ev.w - xv.w;
    float4 o;
    o.x = xv.x + da; o.y = xv.y + db; o.z = xv.z + dc; o.w = xv.w + dd;
    reinterpret_cast<float4*>(out)[(size_t)row * 16 + q16] = o;
    lacc += da * da + db * db + dc * dc + dd * dd;
    if (q16 == 0) out[(size_t)NROWS * DDIM + row] = (float)bi;
  }
  #pragma unroll
  for (int off = 32; off > 0; off >>= 1) lacc += __shfl_down(lacc, off, 64);
  if (l == 0) wsum[wid] = lacc;
  __syncthreads();
  if (tid == 0) {
    atomicAdd(loss_accum, (double)(wsum[0] + wsum[1] + wsum[2] + wsum[3]));
    __threadfence();
    if (atomicAdd(&cnts[1], 1) == (int)gridDim.x - 1) {   // last block: scalars
      __threadfence();
      const double mm = *loss_accum / (double)((size_t)NROWS * DDIM);
      const float el = (float)mm;
      float* tail = out + (size_t)NROWS * DDIM + NROWS;
      tail[0] = 0.25f * el;
      tail[1] = el;
      tail[2] = 0.0f;
    }
  }
}

// ============================================================================
extern "C" void kernel_launch(void* const* d_in, const int* in_sizes, int n_in,
                              void* d_out, int out_size, void* d_ws, size_t ws_size,
                              hipStream_t stream) {
  const float* x   = (const float*)d_in[0];  // [N, 64]
  const float* emb = (const float*)d_in[1];  // [K, 64]
  float* out = (float*)d_out;
  char* ws = (char*)d_ws;

  double* loss_accum = (double*)(ws + WS_LOSS);
  int*    cnts       = (int*)(ws + WS_CNT);   // [0]=full-scan n, [1]=done
  float*  se         = (float*)(ws + WS_SE);
  short*  ehB        = (short*)(ws + WS_EHB);
  short*  elB        = (short*)(ws + WS_ELB);
  int*    bidx       = (int*)(ws + WS_BIDX);
  int*    list       = (int*)(ws + WS_LIST);
  u64*    keyBest    = (u64*)(ws + WS_KEY);
  float2* mv         = (float2*)(ws + WS_MV);
  u64*    kv         = (u64*)(ws + WS_KV);

  vq_prep<<<32, 256, 0, stream>>>(emb, se, ehB, elB, loss_accum, cnts);
  vq_fused<<<(NROWS / 128) * 4, 256, 0, stream>>>(x, ehB, elB, se, mv, kv);
  vq_combine<<<NROWS / 256, 256, 0, stream>>>(mv, kv, bidx, list, cnts, keyBest);
  vq_exact<<<2048, 64, 0, stream>>>(x, emb, se, list, cnts, keyBest);
  vq_finalize<<<NROWS / 64, 256, 0, stream>>>(x, emb, bidx, keyBest, out,
                                              loss_accum, cnts);
}

// Round 17
// 98.730 us; speedup vs baseline: 1.4849x; 1.1466x over previous
//
#include <hip/hip_runtime.h>
#include <hip/hip_bf16.h>
#include <math.h>

// VQ-VAE VectorQuantizer: B=32,T=2048,D=64,K=1024 -> N=65536 rows.
// Round 17: byte-for-byte restore of Round 13 (98.7us, absmax 0.0) -- the
// measured optimum. R14 (B-reuse x2), R15 (top-2 tracking), R16 (chain-split)
// each left fused at ~44.5us or regressed downstream; all reverted.
// Structure: MFMA hi/lo-split distance sweep (min1/min2 certificate, K-split
// x4, per-quarter partials) -> exact 4-way tournament combine + compaction ->
// exact R1-chain scan for ambiguous rows (1-wave blocks, 32-code LDS parts)
// -> fused gather/ST/loss finalize -> scalars.

typedef __attribute__((ext_vector_type(8))) short bf16x8;
typedef __attribute__((ext_vector_type(4))) float f32x4;

namespace {
constexpr int NROWS  = 65536;
constexpr int DDIM   = 64;
constexpr int KCODES = 1024;
constexpr float EPSB = 4e-5f;   // certificate band; bound ~1.05e-5

// ws layout (bytes) — ~7.6 MB
constexpr size_t WS_LOSS = 0;                            // double
constexpr size_t WS_CNT  = 64;                           // int
constexpr size_t WS_SE   = 256;                          // float[1024]
constexpr size_t WS_EHB  = 8192;                         // bf16 frags 128 KB
constexpr size_t WS_ELB  = WS_EHB + (size_t)65536 * 2;   // 128 KB
constexpr size_t WS_BIDX = WS_ELB + (size_t)65536 * 2;   // int[N]
constexpr size_t WS_LIST = WS_BIDX + (size_t)NROWS * 4;  // int[N]
constexpr size_t WS_KEY  = WS_LIST + (size_t)NROWS * 4;  // u64[N]
constexpr size_t WS_MV   = WS_KEY + (size_t)NROWS * 8;   // float2[4][N]
constexpr size_t WS_KV   = WS_MV + (size_t)4 * NROWS * 8; // u64[4][N]
}

__device__ inline short f2bf(float v) {
  __hip_bfloat16 h = __float2bfloat16(v);
  return *reinterpret_cast<short*>(&h);
}
__device__ inline float bf2f(short s) {
  __hip_bfloat16 h;
  *reinterpret_cast<short*>(&h) = s;
  return __bfloat162float(h);
}
__device__ inline f32x4 mfma16(bf16x8 a, bf16x8 b, f32x4 c) {
  return __builtin_amdgcn_mfma_f32_16x16x32_bf16(a, b, c, 0, 0, 0);
}
__device__ inline unsigned int fflip(unsigned int b) {
  return b ^ ((unsigned int)((int)b >> 31) | 0x80000000u);
}

// ---------------- prep: init keyBest/loss/cnt, se (numpy pairwise), frag pack
__global__ __launch_bounds__(256) void vq_prep(const float* __restrict__ emb,
                                               float* __restrict__ se,
                                               short* __restrict__ ehB,
                                               short* __restrict__ elB,
                                               unsigned long long* __restrict__ keyBest,
                                               double* __restrict__ loss_accum,
                                               int* __restrict__ cnt) {
  #pragma clang fp contract(off)
  const int gid = blockIdx.x * 256 + (int)threadIdx.x;   // grid = 65536
  if (gid == 0) { *loss_accum = 0.0; *cnt = 0; }
  keyBest[gid] = ~0ull;

  if (gid < KCODES) {   // se[j]: proven pairwise pattern
    const float* e = emb + (size_t)gid * DDIM;
    float r[8];
    #pragma unroll
    for (int j = 0; j < 8; ++j) r[j] = e[j] * e[j];
    #pragma unroll
    for (int i = 8; i < DDIM; i += 8) {
      #pragma unroll
      for (int j = 0; j < 8; ++j) r[j] += e[i + j] * e[i + j];
    }
    se[gid] = ((r[0] + r[1]) + (r[2] + r[3])) + ((r[4] + r[5]) + (r[6] + r[7]));
  }

  // pack frag (t,dc): lane l holds e[t*16+(l&15)][dc*32+(l>>4)*8 + i]  (R5-R16)
  if (gid < 8192) {
    const int t  = gid >> 7;
    const int dc = (gid >> 6) & 1;
    const int l  = gid & 63;
    const int code = t * 16 + (l & 15);
    const int d0   = dc * 32 + (l >> 4) * 8;
    const float* ep = emb + (size_t)code * DDIM + d0;
    const size_t ob = ((size_t)(t * 2 + dc) * 64 + l) * 8;
    #pragma unroll
    for (int i = 0; i < 8; ++i) {
      const float v = ep[i];
      const short h = f2bf(v);
      ehB[ob + i] = h;
      elB[ob + i] = f2bf(v - bf2f(h));
    }
  }
}

// ---------------- fused sweep: block = 128 rows x 256 codes (K-split x4)
__global__ __launch_bounds__(256, 2) void vq_fused(const float* __restrict__ x,
                                                   const short* __restrict__ ehB,
                                                   const short* __restrict__ elB,
                                                   const float* __restrict__ se,
                                                   float2* __restrict__ mv,
                                                   unsigned long long* __restrict__ kv) {
  #pragma clang fp contract(off)
  __shared__ float sel[256];                     // this quarter's se values
  const int tid  = (int)threadIdx.x;
  const int l    = tid & 63;
  const int wid  = tid >> 6;
  const int quar = (int)blockIdx.x & 3;          // K-quarter: tiles [q*16, q*16+16)
  const int rblk = (int)blockIdx.x >> 2;
  const int t0   = quar * 16;
  sel[tid] = se[t0 * 16 + tid];
  __syncthreads();

  // A-fragments for 2 row-tiles (32 rows/wave)
  const int wrb = rblk * 128 + wid * 32;
  bf16x8 xh[2][2], xl[2][2];
  #pragma unroll
  for (int rt = 0; rt < 2; ++rt) {
    const float* xp = x + (size_t)(wrb + rt * 16 + (l & 15)) * DDIM + (l >> 4) * 8;
    #pragma unroll
    for (int dc = 0; dc < 2; ++dc) {
      const float4 v0 = *reinterpret_cast<const float4*>(xp + dc * 32);
      const float4 v1 = *reinterpret_cast<const float4*>(xp + dc * 32 + 4);
      const float vv[8] = {v0.x, v0.y, v0.z, v0.w, v1.x, v1.y, v1.z, v1.w};
      #pragma unroll
      for (int i = 0; i < 8; ++i) {
        const short h = f2bf(vv[i]);
        xh[rt][dc][i] = h;
        xl[rt][dc][i] = f2bf(vv[i] - bf2f(h));
      }
    }
  }

  float m1v[2][4], m2v[2][4];
  int   m1t[2][4];
  #pragma unroll
  for (int rt = 0; rt < 2; ++rt)
    #pragma unroll
    for (int r = 0; r < 4; ++r) { m1v[rt][r] = INFINITY; m2v[rt][r] = INFINITY; m1t[rt][r] = 0; }

  const size_t lb = (size_t)l * 8;
#define FRAGLD(buf, tt, half2) \
  (*reinterpret_cast<const bf16x8*>((buf) + (size_t)(tt) * 1024 + (half2) * 512 + lb))

  // 2-deep pipeline: tiles t (cur) / t+1 (nxt) in flight while computing.
  bf16x8 c0 = FRAGLD(ehB, t0, 0), c1 = FRAGLD(ehB, t0, 1),
         c2 = FRAGLD(elB, t0, 0), c3 = FRAGLD(elB, t0, 1);
  bf16x8 n0 = FRAGLD(ehB, t0 + 1, 0), n1 = FRAGLD(ehB, t0 + 1, 1),
         n2 = FRAGLD(elB, t0 + 1, 0), n3 = FRAGLD(elB, t0 + 1, 1);

  const f32x4 kz = {0.f, 0.f, 0.f, 0.f};
  #pragma unroll 4
  for (int tt = 0; tt < 16; ++tt) {
    const int t = t0 + tt;
    const int tf = (tt + 2 < 16) ? t + 2 : t0 + 15;   // clamp (dup loads harmless)
    bf16x8 f0 = FRAGLD(ehB, tf, 0), f1 = FRAGLD(ehB, tf, 1),
           f2 = FRAGLD(elB, tf, 0), f3 = FRAGLD(elB, tf, 1);

    f32x4 a0, a1;   // interleave the two row-tiles: dep distance 2 on MFMA pipe
    a0 = mfma16(xh[0][0], c0, kz);  a1 = mfma16(xh[1][0], c0, kz);
    a0 = mfma16(xh[0][1], c1, a0);  a1 = mfma16(xh[1][1], c1, a1);
    a0 = mfma16(xh[0][0], c2, a0);  a1 = mfma16(xh[1][0], c2, a1);
    a0 = mfma16(xh[0][1], c3, a0);  a1 = mfma16(xh[1][1], c3, a1);
    a0 = mfma16(xl[0][0], c0, a0);  a1 = mfma16(xl[1][0], c0, a1);
    a0 = mfma16(xl[0][1], c1, a0);  a1 = mfma16(xl[1][1], c1, a1);

    const float sev = sel[tt * 16 + (l & 15)];
    #pragma unroll
    for (int r = 0; r < 4; ++r) {
      {
        const float d = __builtin_fmaf(-2.0f, a0[r], sev);  // d' = se - 2*dot
        const bool c = d < m1v[0][r];
        m2v[0][r] = fminf(m2v[0][r], fmaxf(m1v[0][r], d));
        m1t[0][r] = c ? t : m1t[0][r];
        m1v[0][r] = fminf(m1v[0][r], d);
      }
      {
        const float d = __builtin_fmaf(-2.0f, a1[r], sev);
        const bool c = d < m1v[1][r];
        m2v[1][r] = fminf(m2v[1][r], fmaxf(m1v[1][r], d));
        m1t[1][r] = c ? t : m1t[1][r];
        m1v[1][r] = fminf(m1v[1][r], d);
      }
    }
    c0 = n0; c1 = n1; c2 = n2; c3 = n3;
    n0 = f0; n1 = f1; n2 = f2; n3 = f3;
  }
#undef FRAGLD

  // 16-lane merge (R6-R13-proven); emit per-quarter partials
  const int colbase = l & 15;
  #pragma unroll
  for (int rt = 0; rt < 2; ++rt) {
    #pragma unroll
    for (int r = 0; r < 4; ++r) {
      float m1 = m1v[rt][r], m2 = m2v[rt][r];
      unsigned long long key =
          ((unsigned long long)fflip(__float_as_uint(m1)) << 32)
          | (unsigned)(m1t[rt][r] * 16 + colbase);
      #pragma unroll
      for (int off = 1; off < 16; off <<= 1) {
        const unsigned long long ok = __shfl_xor(key, off, 16);
        const float om1 = __shfl_xor(m1, off, 16);
        const float om2 = __shfl_xor(m2, off, 16);
        m2 = fminf(fminf(m2, om2), fmaxf(m1, om1));
        m1 = fminf(m1, om1);
        key = (ok < key) ? ok : key;
      }
      if (colbase == 0) {
        const int row = wrb + rt * 16 + (l >> 4) * 4 + r;
        mv[(size_t)quar * NROWS + row] = make_float2(m1, m2);
        kv[(size_t)quar * NROWS + row] = key;
      }
    }
  }
}

// ---------------- combine 4 quarters + certificate + ballot compaction
__global__ __launch_bounds__(256) void vq_combine(const float2* __restrict__ mv,
                                                  const unsigned long long* __restrict__ kv,
                                                  int* __restrict__ bidx,
                                                  int* __restrict__ list,
                                                  int* __restrict__ cnt) {
  const int gid = blockIdx.x * 256 + (int)threadIdx.x;
  const int l = (int)threadIdx.x & 63;
  const float2 A = mv[gid];
  const float2 B = mv[(size_t)NROWS + gid];
  const float2 C = mv[(size_t)2 * NROWS + gid];
  const float2 D = mv[(size_t)3 * NROWS + gid];
  unsigned long long kg = kv[gid];
  {
    unsigned long long k2 = kv[(size_t)NROWS + gid];     kg = (k2 < kg) ? k2 : kg;
    k2 = kv[(size_t)2 * NROWS + gid];                    kg = (k2 < kg) ? k2 : kg;
    k2 = kv[(size_t)3 * NROWS + gid];                    kg = (k2 < kg) ? k2 : kg;
  }
  // union's two smallest over 4 disjoint quarters (exact tournament rule)
  const float lo1 = fminf(A.x, B.x), hi1 = fmaxf(A.x, B.x);
  const float lo2 = fminf(C.x, D.x), hi2 = fmaxf(C.x, D.x);
  const float m1g = fminf(lo1, lo2);
  const float sec = fminf(fmaxf(lo1, lo2), fminf(hi1, hi2));  // secondmin{m1}
  const float m2g = fminf(sec, fminf(fminf(A.y, B.y), fminf(C.y, D.y)));
  const bool cert = m2g > m1g + EPSB;
  bidx[gid] = cert ? (int)(kg & 0xffffffffull) : -1;

  const unsigned long long mask = __ballot(!cert);
  int base = 0;
  if (l == 0 && mask) base = atomicAdd(cnt, (int)__popcll(mask));
  base = __shfl(base, 0, 64);
  if (!cert) {
    const int off = (int)__popcll(mask & ((1ull << l) - 1ull));
    list[base + off] = gid;
  }
}

// ---------------- exact scan: 1-wave blocks, lanes = rows, 32-code LDS parts,
// grid-strided tasks. Per-(row,code) arithmetic verbatim R11-R13.
__global__ __launch_bounds__(64) void vq_exact(const float* __restrict__ x,
                                               const float* __restrict__ emb,
                                               const float* __restrict__ se,
                                               const int* __restrict__ list,
                                               const int* __restrict__ cnt,
                                               unsigned long long* __restrict__ keyBest) {
  #pragma clang fp contract(off)
  __shared__ __align__(16) float eL[32 * DDIM];   // 8 KB: one part's 32 codes
  const int n = *cnt;
  if (n == 0) return;
  const int nrb = (n + 63) >> 6;
  const int ntasks = nrb * 32;
  const int l = (int)threadIdx.x;                 // 0..63

  for (int t = (int)blockIdx.x; t < ntasks; t += (int)gridDim.x) {
    const int part = t & 31;
    const int rb   = t >> 5;
    const int j0   = part * 32;

    {  // stage this part's 32 e-rows (coalesced float4)
      const float4* src = reinterpret_cast<const float4*>(emb + (size_t)j0 * DDIM);
      float4* dst = reinterpret_cast<float4*>(eL);
      #pragma unroll
      for (int i = 0; i < 8; ++i) dst[i * 64 + l] = src[i * 64 + l];
    }
    __syncthreads();

    const int idx = rb * 64 + l;
    const bool act = idx < n;
    const int row = act ? list[idx] : 0;
    const float4* xr4 = reinterpret_cast<const float4*>(x + (size_t)row * DDIM);

    float xv[DDIM];   // x row -> regs once
    #pragma unroll
    for (int q = 0; q < 16; ++q) {
      const float4 v = xr4[q];
      xv[q * 4 + 0] = v.x; xv[q * 4 + 1] = v.y;
      xv[q * 4 + 2] = v.z; xv[q * 4 + 3] = v.w;
    }

    // sx: numpy pairwise 8-accumulator (R1-proven order)
    float rr[8];
    #pragma unroll
    for (int j = 0; j < 8; ++j) rr[j] = xv[j] * xv[j];
    #pragma unroll
    for (int i = 8; i < DDIM; i += 8) {
      #pragma unroll
      for (int j = 0; j < 8; ++j) rr[j] += xv[i + j] * xv[i + j];
    }
    const float sx = ((rr[0] + rr[1]) + (rr[2] + rr[3])) + ((rr[4] + rr[5]) + (rr[6] + rr[7]));

    unsigned long long best = ~0ull;
    #pragma unroll 1
    for (int g = 0; g < 8; ++g) {   // 8 groups of 4 codes; 4 chains
      const int jb = g * 4;
      const float4* e0 = reinterpret_cast<const float4*>(eL + (jb + 0) * DDIM);
      const float4* e1 = reinterpret_cast<const float4*>(eL + (jb + 1) * DDIM);
      const float4* e2 = reinterpret_cast<const float4*>(eL + (jb + 2) * DDIM);
      const float4* e3 = reinterpret_cast<const float4*>(eL + (jb + 3) * DDIM);
      float a0 = 0.f, a1 = 0.f, a2 = 0.f, a3 = 0.f;
      #pragma unroll
      for (int q = 0; q < 16; ++q) {   // per code: sequential d=0..63 (R1 chain)
        const float4 v0 = e0[q], v1 = e1[q], v2 = e2[q], v3 = e3[q];
        const float xa = xv[q * 4 + 0], xb = xv[q * 4 + 1];
        const float xc = xv[q * 4 + 2], xd = xv[q * 4 + 3];
        a0 = __builtin_fmaf(xa, v0.x, a0); a0 = __builtin_fmaf(xb, v0.y, a0);
        a0 = __builtin_fmaf(xc, v0.z, a0); a0 = __builtin_fmaf(xd, v0.w, a0);
        a1 = __builtin_fmaf(xa, v1.x, a1); a1 = __builtin_fmaf(xb, v1.y, a1);
        a1 = __builtin_fmaf(xc, v1.z, a1); a1 = __builtin_fmaf(xd, v1.w, a1);
        a2 = __builtin_fmaf(xa, v2.x, a2); a2 = __builtin_fmaf(xb, v2.y, a2);
        a2 = __builtin_fmaf(xc, v2.z, a2); a2 = __builtin_fmaf(xd, v2.w, a2);
        a3 = __builtin_fmaf(xa, v3.x, a3); a3 = __builtin_fmaf(xb, v3.y, a3);
        a3 = __builtin_fmaf(xc, v3.z, a3); a3 = __builtin_fmaf(xd, v3.w, a3);
      }
      const int j = j0 + jb;
      const float T0 = sx + se[j + 0];                    // fl(sx + se_j)
      const float T1 = sx + se[j + 1];
      const float T2 = sx + se[j + 2];
      const float T3 = sx + se[j + 3];
      const float di0 = __builtin_fmaf(-2.0f, a0, T0);    // fl(T - 2*acc)
      const float di1 = __builtin_fmaf(-2.0f, a1, T1);
      const float di2 = __builtin_fmaf(-2.0f, a2, T2);
      const float di3 = __builtin_fmaf(-2.0f, a3, T3);
      unsigned long long k;
      k = ((unsigned long long)fflip(__float_as_uint(di0)) << 32) | (unsigned)(j + 0);
      best = (k < best) ? k : best;
      k = ((unsigned long long)fflip(__float_as_uint(di1)) << 32) | (unsigned)(j + 1);
      best = (k < best) ? k : best;
      k = ((unsigned long long)fflip(__float_as_uint(di2)) << 32) | (unsigned)(j + 2);
      best = (k < best) ? k : best;
      k = ((unsigned long long)fflip(__float_as_uint(di3)) << 32) | (unsigned)(j + 3);
      best = (k < best) ? k : best;
    }
    if (act) atomicMin(&keyBest[row], best);   // (dist asc, j asc) == first-min
    __syncthreads();                           // eL reuse barrier (1-wave: cheap)
  }
}

// ---------------- finalize: 16 lanes x float4 per row (coalesced e-gather)
__global__ __launch_bounds__(256) void vq_finalize(const float* __restrict__ x,
                                                   const float* __restrict__ emb,
                                                   const int* __restrict__ bidx,
                                                   const unsigned long long* __restrict__ keyBest,
                                                   float* __restrict__ out,
                                                   double* __restrict__ loss_accum) {
  #pragma clang fp contract(off)
  __shared__ float wsum[4];
  const int tid = (int)threadIdx.x;
  const int l   = tid & 63;
  const int wid = tid >> 6;
  const int sub = l >> 4;    // row within the wave's quad
  const int q16 = l & 15;    // float4 slot within the row
  float lacc = 0.f;

  #pragma unroll
  for (int it = 0; it < 4; ++it) {   // block covers 64 rows
    const int row = blockIdx.x * 64 + it * 16 + wid * 4 + sub;
    int bi = bidx[row];
    if (bi < 0) bi = (int)(keyBest[row] & 0xffffffffull);
    const float4 xv = reinterpret_cast<const float4*>(x)[(size_t)row * 16 + q16];
    const float4 ev = reinterpret_cast<const float4*>(emb)[(size_t)bi * 16 + q16];
    const float da = ev.x - xv.x;
    const float db = ev.y - xv.y;
    const float dc = ev.z - xv.z;
    const float dd = ev.w - xv.w;
    float4 o;
    o.x = xv.x + da; o.y = xv.y + db; o.z = xv.z + dc; o.w = xv.w + dd;
    reinterpret_cast<float4*>(out)[(size_t)row * 16 + q16] = o;
    lacc += da * da + db * db + dc * dc + dd * dd;   // order-insensitive
    if (q16 == 0) out[(size_t)NROWS * DDIM + row] = (float)bi;
  }
  #pragma unroll
  for (int off = 32; off > 0; off >>= 1) lacc += __shfl_down(lacc, off, 64);
  if (l == 0) wsum[wid] = lacc;
  __syncthreads();
  if (tid == 0)
    atomicAdd(loss_accum, (double)(wsum[0] + wsum[1] + wsum[2] + wsum[3]));
}

// ---------------- scalars
__global__ void vq_scalars(const double* __restrict__ loss_accum,
                           float* __restrict__ out) {
  if (threadIdx.x == 0 && blockIdx.x == 0) {
    const double mm = *loss_accum / (double)((size_t)NROWS * DDIM);
    const float el = (float)mm;
    float* tail = out + (size_t)NROWS * DDIM + NROWS;
    tail[0] = 0.25f * el;
    tail[1] = el;
    tail[2] = 0.0f;
  }
}

// ============================================================================
extern "C" void kernel_launch(void* const* d_in, const int* in_sizes, int n_in,
                              void* d_out, int out_size, void* d_ws, size_t ws_size,
                              hipStream_t stream) {
  const float* x   = (const float*)d_in[0];  // [N, 64]
  const float* emb = (const float*)d_in[1];  // [K, 64]
  float* out = (float*)d_out;
  char* ws = (char*)d_ws;

  double* loss_accum = (double*)(ws + WS_LOSS);
  int*    cnt        = (int*)(ws + WS_CNT);
  float*  se         = (float*)(ws + WS_SE);
  short*  ehB        = (short*)(ws + WS_EHB);
  short*  elB        = (short*)(ws + WS_ELB);
  int*    bidx       = (int*)(ws + WS_BIDX);
  int*    list       = (int*)(ws + WS_LIST);
  unsigned long long* keyBest = (unsigned long long*)(ws + WS_KEY);
  float2* mv         = (float2*)(ws + WS_MV);
  unsigned long long* kv = (unsigned long long*)(ws + WS_KV);

  vq_prep<<<NROWS / 256, 256, 0, stream>>>(emb, se, ehB, elB, keyBest,
                                           loss_accum, cnt);
  vq_fused<<<(NROWS / 128) * 4, 256, 0, stream>>>(x, ehB, elB, se, mv, kv);
  vq_combine<<<NROWS / 256, 256, 0, stream>>>(mv, kv, bidx, list, cnt);
  vq_exact<<<2048, 64, 0, stream>>>(x, emb, se, list, cnt, keyBest);
  vq_finalize<<<NROWS / 64, 256, 0, stream>>>(x, emb, bidx, keyBest, out,
                                              loss_accum);
  vq_scalars<<<1, 64, 0, stream>>>(loss_accum, out);
}

// Round 18
// 94.253 us; speedup vs baseline: 1.5555x; 1.0475x over previous
//
#include <hip/hip_runtime.h>
#include <hip/hip_bf16.h>
#include <math.h>

// VQ-VAE VectorQuantizer: B=32,T=2048,D=64,K=1024 -> N=65536 rows.
// Round 18: R13/R17 pipeline (98.7us reproducible, absmax 0.0) with the
// finalize pass folded into combine for certified rows (~96%):
//  - vq_combine_out: R13 tournament+compaction verbatim, verdict stashed in
//    LDS; phase 2 in-kernel writes gather/ST/index/loss for certified rows
//    (finalize's proven arithmetic + coalesced 16-lane float4 pattern).
//  - vq_minifinal: grid-strided over ambiguous list only (keyBest lookup),
//    same proven arithmetic. ~4k rows.
//  - NO device-scope fences (R15/R16 post-mortem: per-block __threadfence
//    in finalize was the hidden +14-19us regressor). Scalars stays separate.
// prep / fused / exact / scalars: R13-verbatim.

typedef __attribute__((ext_vector_type(8))) short bf16x8;
typedef __attribute__((ext_vector_type(4))) float f32x4;

namespace {
constexpr int NROWS  = 65536;
constexpr int DDIM   = 64;
constexpr int KCODES = 1024;
constexpr float EPSB = 4e-5f;   // certificate band; bound ~1.05e-5

// ws layout (bytes) — ~7.6 MB
constexpr size_t WS_LOSS = 0;                            // double
constexpr size_t WS_CNT  = 64;                           // int
constexpr size_t WS_SE   = 256;                          // float[1024]
constexpr size_t WS_EHB  = 8192;                         // bf16 frags 128 KB
constexpr size_t WS_ELB  = WS_EHB + (size_t)65536 * 2;   // 128 KB
constexpr size_t WS_BIDX = WS_ELB + (size_t)65536 * 2;   // int[N] (unused, kept)
constexpr size_t WS_LIST = WS_BIDX + (size_t)NROWS * 4;  // int[N]
constexpr size_t WS_KEY  = WS_LIST + (size_t)NROWS * 4;  // u64[N]
constexpr size_t WS_MV   = WS_KEY + (size_t)NROWS * 8;   // float2[4][N]
constexpr size_t WS_KV   = WS_MV + (size_t)4 * NROWS * 8; // u64[4][N]
}

__device__ inline short f2bf(float v) {
  __hip_bfloat16 h = __float2bfloat16(v);
  return *reinterpret_cast<short*>(&h);
}
__device__ inline float bf2f(short s) {
  __hip_bfloat16 h;
  *reinterpret_cast<short*>(&h) = s;
  return __bfloat162float(h);
}
__device__ inline f32x4 mfma16(bf16x8 a, bf16x8 b, f32x4 c) {
  return __builtin_amdgcn_mfma_f32_16x16x32_bf16(a, b, c, 0, 0, 0);
}
__device__ inline unsigned int fflip(unsigned int b) {
  return b ^ ((unsigned int)((int)b >> 31) | 0x80000000u);
}

// ---------------- prep: init keyBest/loss/cnt, se (numpy pairwise), frag pack
__global__ __launch_bounds__(256) void vq_prep(const float* __restrict__ emb,
                                               float* __restrict__ se,
                                               short* __restrict__ ehB,
                                               short* __restrict__ elB,
                                               unsigned long long* __restrict__ keyBest,
                                               double* __restrict__ loss_accum,
                                               int* __restrict__ cnt) {
  #pragma clang fp contract(off)
  const int gid = blockIdx.x * 256 + (int)threadIdx.x;   // grid = 65536
  if (gid == 0) { *loss_accum = 0.0; *cnt = 0; }
  keyBest[gid] = ~0ull;

  if (gid < KCODES) {   // se[j]: proven pairwise pattern
    const float* e = emb + (size_t)gid * DDIM;
    float r[8];
    #pragma unroll
    for (int j = 0; j < 8; ++j) r[j] = e[j] * e[j];
    #pragma unroll
    for (int i = 8; i < DDIM; i += 8) {
      #pragma unroll
      for (int j = 0; j < 8; ++j) r[j] += e[i + j] * e[i + j];
    }
    se[gid] = ((r[0] + r[1]) + (r[2] + r[3])) + ((r[4] + r[5]) + (r[6] + r[7]));
  }

  // pack frag (t,dc): lane l holds e[t*16+(l&15)][dc*32+(l>>4)*8 + i]  (R5-R17)
  if (gid < 8192) {
    const int t  = gid >> 7;
    const int dc = (gid >> 6) & 1;
    const int l  = gid & 63;
    const int code = t * 16 + (l & 15);
    const int d0   = dc * 32 + (l >> 4) * 8;
    const float* ep = emb + (size_t)code * DDIM + d0;
    const size_t ob = ((size_t)(t * 2 + dc) * 64 + l) * 8;
    #pragma unroll
    for (int i = 0; i < 8; ++i) {
      const float v = ep[i];
      const short h = f2bf(v);
      ehB[ob + i] = h;
      elB[ob + i] = f2bf(v - bf2f(h));
    }
  }
}

// ---------------- fused sweep: block = 128 rows x 256 codes (K-split x4)
__global__ __launch_bounds__(256, 2) void vq_fused(const float* __restrict__ x,
                                                   const short* __restrict__ ehB,
                                                   const short* __restrict__ elB,
                                                   const float* __restrict__ se,
                                                   float2* __restrict__ mv,
                                                   unsigned long long* __restrict__ kv) {
  #pragma clang fp contract(off)
  __shared__ float sel[256];                     // this quarter's se values
  const int tid  = (int)threadIdx.x;
  const int l    = tid & 63;
  const int wid  = tid >> 6;
  const int quar = (int)blockIdx.x & 3;          // K-quarter: tiles [q*16, q*16+16)
  const int rblk = (int)blockIdx.x >> 2;
  const int t0   = quar * 16;
  sel[tid] = se[t0 * 16 + tid];
  __syncthreads();

  // A-fragments for 2 row-tiles (32 rows/wave)
  const int wrb = rblk * 128 + wid * 32;
  bf16x8 xh[2][2], xl[2][2];
  #pragma unroll
  for (int rt = 0; rt < 2; ++rt) {
    const float* xp = x + (size_t)(wrb + rt * 16 + (l & 15)) * DDIM + (l >> 4) * 8;
    #pragma unroll
    for (int dc = 0; dc < 2; ++dc) {
      const float4 v0 = *reinterpret_cast<const float4*>(xp + dc * 32);
      const float4 v1 = *reinterpret_cast<const float4*>(xp + dc * 32 + 4);
      const float vv[8] = {v0.x, v0.y, v0.z, v0.w, v1.x, v1.y, v1.z, v1.w};
      #pragma unroll
      for (int i = 0; i < 8; ++i) {
        const short h = f2bf(vv[i]);
        xh[rt][dc][i] = h;
        xl[rt][dc][i] = f2bf(vv[i] - bf2f(h));
      }
    }
  }

  float m1v[2][4], m2v[2][4];
  int   m1t[2][4];
  #pragma unroll
  for (int rt = 0; rt < 2; ++rt)
    #pragma unroll
    for (int r = 0; r < 4; ++r) { m1v[rt][r] = INFINITY; m2v[rt][r] = INFINITY; m1t[rt][r] = 0; }

  const size_t lb = (size_t)l * 8;
#define FRAGLD(buf, tt, half2) \
  (*reinterpret_cast<const bf16x8*>((buf) + (size_t)(tt) * 1024 + (half2) * 512 + lb))

  // 2-deep pipeline: tiles t (cur) / t+1 (nxt) in flight while computing.
  bf16x8 c0 = FRAGLD(ehB, t0, 0), c1 = FRAGLD(ehB, t0, 1),
         c2 = FRAGLD(elB, t0, 0), c3 = FRAGLD(elB, t0, 1);
  bf16x8 n0 = FRAGLD(ehB, t0 + 1, 0), n1 = FRAGLD(ehB, t0 + 1, 1),
         n2 = FRAGLD(elB, t0 + 1, 0), n3 = FRAGLD(elB, t0 + 1, 1);

  const f32x4 kz = {0.f, 0.f, 0.f, 0.f};
  #pragma unroll 4
  for (int tt = 0; tt < 16; ++tt) {
    const int t = t0 + tt;
    const int tf = (tt + 2 < 16) ? t + 2 : t0 + 15;   // clamp (dup loads harmless)
    bf16x8 f0 = FRAGLD(ehB, tf, 0), f1 = FRAGLD(ehB, tf, 1),
           f2 = FRAGLD(elB, tf, 0), f3 = FRAGLD(elB, tf, 1);

    f32x4 a0, a1;   // interleave the two row-tiles: dep distance 2 on MFMA pipe
    a0 = mfma16(xh[0][0], c0, kz);  a1 = mfma16(xh[1][0], c0, kz);
    a0 = mfma16(xh[0][1], c1, a0);  a1 = mfma16(xh[1][1], c1, a1);
    a0 = mfma16(xh[0][0], c2, a0);  a1 = mfma16(xh[1][0], c2, a1);
    a0 = mfma16(xh[0][1], c3, a0);  a1 = mfma16(xh[1][1], c3, a1);
    a0 = mfma16(xl[0][0], c0, a0);  a1 = mfma16(xl[1][0], c0, a1);
    a0 = mfma16(xl[0][1], c1, a0);  a1 = mfma16(xl[1][1], c1, a1);

    const float sev = sel[tt * 16 + (l & 15)];
    #pragma unroll
    for (int r = 0; r < 4; ++r) {
      {
        const float d = __builtin_fmaf(-2.0f, a0[r], sev);  // d' = se - 2*dot
        const bool c = d < m1v[0][r];
        m2v[0][r] = fminf(m2v[0][r], fmaxf(m1v[0][r], d));
        m1t[0][r] = c ? t : m1t[0][r];
        m1v[0][r] = fminf(m1v[0][r], d);
      }
      {
        const float d = __builtin_fmaf(-2.0f, a1[r], sev);
        const bool c = d < m1v[1][r];
        m2v[1][r] = fminf(m2v[1][r], fmaxf(m1v[1][r], d));
        m1t[1][r] = c ? t : m1t[1][r];
        m1v[1][r] = fminf(m1v[1][r], d);
      }
    }
    c0 = n0; c1 = n1; c2 = n2; c3 = n3;
    n0 = f0; n1 = f1; n2 = f2; n3 = f3;
  }
#undef FRAGLD

  // 16-lane merge (R6-R17-proven); emit per-quarter partials
  const int colbase = l & 15;
  #pragma unroll
  for (int rt = 0; rt < 2; ++rt) {
    #pragma unroll
    for (int r = 0; r < 4; ++r) {
      float m1 = m1v[rt][r], m2 = m2v[rt][r];
      unsigned long long key =
          ((unsigned long long)fflip(__float_as_uint(m1)) << 32)
          | (unsigned)(m1t[rt][r] * 16 + colbase);
      #pragma unroll
      for (int off = 1; off < 16; off <<= 1) {
        const unsigned long long ok = __shfl_xor(key, off, 16);
        const float om1 = __shfl_xor(m1, off, 16);
        const float om2 = __shfl_xor(m2, off, 16);
        m2 = fminf(fminf(m2, om2), fmaxf(m1, om1));
        m1 = fminf(m1, om1);
        key = (ok < key) ? ok : key;
      }
      if (colbase == 0) {
        const int row = wrb + rt * 16 + (l >> 4) * 4 + r;
        mv[(size_t)quar * NROWS + row] = make_float2(m1, m2);
        kv[(size_t)quar * NROWS + row] = key;
      }
    }
  }
}

// ---------------- combine + certified-row finalize (fused)
__global__ __launch_bounds__(256) void vq_combine_out(const float2* __restrict__ mv,
                                                      const unsigned long long* __restrict__ kv,
                                                      const float* __restrict__ x,
                                                      const float* __restrict__ emb,
                                                      int* __restrict__ list,
                                                      int* __restrict__ cnt,
                                                      float* __restrict__ out,
                                                      double* __restrict__ loss_accum) {
  #pragma clang fp contract(off)
  __shared__ int   sbidx[256];
  __shared__ float wsum[4];
  const int tid = (int)threadIdx.x;
  const int gid = blockIdx.x * 256 + tid;
  const int l   = tid & 63;

  // ---- phase 1: R13 tournament + compaction (verbatim logic)
  {
    const float2 A = mv[gid];
    const float2 B = mv[(size_t)NROWS + gid];
    const float2 C = mv[(size_t)2 * NROWS + gid];
    const float2 D = mv[(size_t)3 * NROWS + gid];
    unsigned long long kg = kv[gid];
    {
      unsigned long long k2 = kv[(size_t)NROWS + gid];     kg = (k2 < kg) ? k2 : kg;
      k2 = kv[(size_t)2 * NROWS + gid];                    kg = (k2 < kg) ? k2 : kg;
      k2 = kv[(size_t)3 * NROWS + gid];                    kg = (k2 < kg) ? k2 : kg;
    }
    const float lo1 = fminf(A.x, B.x), hi1 = fmaxf(A.x, B.x);
    const float lo2 = fminf(C.x, D.x), hi2 = fmaxf(C.x, D.x);
    const float m1g = fminf(lo1, lo2);
    const float sec = fminf(fmaxf(lo1, lo2), fminf(hi1, hi2));  // secondmin{m1}
    const float m2g = fminf(sec, fminf(fminf(A.y, B.y), fminf(C.y, D.y)));
    const bool cert = m2g > m1g + EPSB;
    sbidx[tid] = cert ? (int)(kg & 0xffffffffull) : -1;

    const unsigned long long mask = __ballot(!cert);
    int base = 0;
    if (l == 0 && mask) base = atomicAdd(cnt, (int)__popcll(mask));
    base = __shfl(base, 0, 64);
    if (!cert) {
      const int off = (int)__popcll(mask & ((1ull << l) - 1ull));
      list[base + off] = gid;
    }
  }
  __syncthreads();

  // ---- phase 2: finalize certified rows (proven finalize arithmetic/pattern)
  const int wid = tid >> 6;
  const int sub = l >> 4;    // row within the wave's quad
  const int q16 = l & 15;    // float4 slot within the row
  float lacc = 0.f;

  for (int it = 0; it < 16; ++it) {   // block covers its 256 rows
    const int rloc = it * 16 + wid * 4 + sub;
    const int bi = sbidx[rloc];       // uniform within the 16-lane group
    if (bi < 0) continue;             // ambiguous -> minifinal handles
    const int row = blockIdx.x * 256 + rloc;
    const float4 xv = reinterpret_cast<const float4*>(x)[(size_t)row * 16 + q16];
    const float4 ev = reinterpret_cast<const float4*>(emb)[(size_t)bi * 16 + q16];
    const float da = ev.x - xv.x;
    const float db = ev.y - xv.y;
    const float dc = ev.z - xv.z;
    const float dd = ev.w - xv.w;
    float4 o;
    o.x = xv.x + da; o.y = xv.y + db; o.z = xv.z + dc; o.w = xv.w + dd;
    reinterpret_cast<float4*>(out)[(size_t)row * 16 + q16] = o;
    lacc += da * da + db * db + dc * dc + dd * dd;   // order-insensitive
    if (q16 == 0) out[(size_t)NROWS * DDIM + row] = (float)bi;
  }
  #pragma unroll
  for (int off = 32; off > 0; off >>= 1) lacc += __shfl_down(lacc, off, 64);
  if (l == 0) wsum[wid] = lacc;
  __syncthreads();
  if (tid == 0)
    atomicAdd(loss_accum, (double)(wsum[0] + wsum[1] + wsum[2] + wsum[3]));
}

// ---------------- exact scan (R13-frozen): 1-wave blocks, 32-code LDS parts
__global__ __launch_bounds__(64) void vq_exact(const float* __restrict__ x,
                                               const float* __restrict__ emb,
                                               const float* __restrict__ se,
                                               const int* __restrict__ list,
                                               const int* __restrict__ cnt,
                                               unsigned long long* __restrict__ keyBest) {
  #pragma clang fp contract(off)
  __shared__ __align__(16) float eL[32 * DDIM];   // 8 KB: one part's 32 codes
  const int n = *cnt;
  if (n == 0) return;
  const int nrb = (n + 63) >> 6;
  const int ntasks = nrb * 32;
  const int l = (int)threadIdx.x;                 // 0..63

  for (int t = (int)blockIdx.x; t < ntasks; t += (int)gridDim.x) {
    const int part = t & 31;
    const int rb   = t >> 5;
    const int j0   = part * 32;

    {  // stage this part's 32 e-rows (coalesced float4)
      const float4* src = reinterpret_cast<const float4*>(emb + (size_t)j0 * DDIM);
      float4* dst = reinterpret_cast<float4*>(eL);
      #pragma unroll
      for (int i = 0; i < 8; ++i) dst[i * 64 + l] = src[i * 64 + l];
    }
    __syncthreads();

    const int idx = rb * 64 + l;
    const bool act = idx < n;
    const int row = act ? list[idx] : 0;
    const float4* xr4 = reinterpret_cast<const float4*>(x + (size_t)row * DDIM);

    float xv[DDIM];   // x row -> regs once
    #pragma unroll
    for (int q = 0; q < 16; ++q) {
      const float4 v = xr4[q];
      xv[q * 4 + 0] = v.x; xv[q * 4 + 1] = v.y;
      xv[q * 4 + 2] = v.z; xv[q * 4 + 3] = v.w;
    }

    // sx: numpy pairwise 8-accumulator (R1-proven order)
    float rr[8];
    #pragma unroll
    for (int j = 0; j < 8; ++j) rr[j] = xv[j] * xv[j];
    #pragma unroll
    for (int i = 8; i < DDIM; i += 8) {
      #pragma unroll
      for (int j = 0; j < 8; ++j) rr[j] += xv[i + j] * xv[i + j];
    }
    const float sx = ((rr[0] + rr[1]) + (rr[2] + rr[3])) + ((rr[4] + rr[5]) + (rr[6] + rr[7]));

    unsigned long long best = ~0ull;
    #pragma unroll 1
    for (int g = 0; g < 8; ++g) {   // 8 groups of 4 codes; 4 chains
      const int jb = g * 4;
      const float4* e0 = reinterpret_cast<const float4*>(eL + (jb + 0) * DDIM);
      const float4* e1 = reinterpret_cast<const float4*>(eL + (jb + 1) * DDIM);
      const float4* e2 = reinterpret_cast<const float4*>(eL + (jb + 2) * DDIM);
      const float4* e3 = reinterpret_cast<const float4*>(eL + (jb + 3) * DDIM);
      float a0 = 0.f, a1 = 0.f, a2 = 0.f, a3 = 0.f;
      #pragma unroll
      for (int q = 0; q < 16; ++q) {   // per code: sequential d=0..63 (R1 chain)
        const float4 v0 = e0[q], v1 = e1[q], v2 = e2[q], v3 = e3[q];
        const float xa = xv[q * 4 + 0], xb = xv[q * 4 + 1];
        const float xc = xv[q * 4 + 2], xd = xv[q * 4 + 3];
        a0 = __builtin_fmaf(xa, v0.x, a0); a0 = __builtin_fmaf(xb, v0.y, a0);
        a0 = __builtin_fmaf(xc, v0.z, a0); a0 = __builtin_fmaf(xd, v0.w, a0);
        a1 = __builtin_fmaf(xa, v1.x, a1); a1 = __builtin_fmaf(xb, v1.y, a1);
        a1 = __builtin_fmaf(xc, v1.z, a1); a1 = __builtin_fmaf(xd, v1.w, a1);
        a2 = __builtin_fmaf(xa, v2.x, a2); a2 = __builtin_fmaf(xb, v2.y, a2);
        a2 = __builtin_fmaf(xc, v2.z, a2); a2 = __builtin_fmaf(xd, v2.w, a2);
        a3 = __builtin_fmaf(xa, v3.x, a3); a3 = __builtin_fmaf(xb, v3.y, a3);
        a3 = __builtin_fmaf(xc, v3.z, a3); a3 = __builtin_fmaf(xd, v3.w, a3);
      }
      const int j = j0 + jb;
      const float T0 = sx + se[j + 0];                    // fl(sx + se_j)
      const float T1 = sx + se[j + 1];
      const float T2 = sx + se[j + 2];
      const float T3 = sx + se[j + 3];
      const float di0 = __builtin_fmaf(-2.0f, a0, T0);    // fl(T - 2*acc)
      const float di1 = __builtin_fmaf(-2.0f, a1, T1);
      const float di2 = __builtin_fmaf(-2.0f, a2, T2);
      const float di3 = __builtin_fmaf(-2.0f, a3, T3);
      unsigned long long k;
      k = ((unsigned long long)fflip(__float_as_uint(di0)) << 32) | (unsigned)(j + 0);
      best = (k < best) ? k : best;
      k = ((unsigned long long)fflip(__float_as_uint(di1)) << 32) | (unsigned)(j + 1);
      best = (k < best) ? k : best;
      k = ((unsigned long long)fflip(__float_as_uint(di2)) << 32) | (unsigned)(j + 2);
      best = (k < best) ? k : best;
      k = ((unsigned long long)fflip(__float_as_uint(di3)) << 32) | (unsigned)(j + 3);
      best = (k < best) ? k : best;
    }
    if (act) atomicMin(&keyBest[row], best);   // (dist asc, j asc) == first-min
    __syncthreads();                           // eL reuse barrier (1-wave: cheap)
  }
}

// ---------------- minifinal: ambiguous rows only (keyBest lookup)
__global__ __launch_bounds__(256) void vq_minifinal(const float* __restrict__ x,
                                                    const float* __restrict__ emb,
                                                    const int* __restrict__ list,
                                                    const int* __restrict__ cnt,
                                                    const unsigned long long* __restrict__ keyBest,
                                                    float* __restrict__ out,
                                                    double* __restrict__ loss_accum) {
  #pragma clang fp contract(off)
  const int n = *cnt;
  const int l   = (int)threadIdx.x & 63;
  const int sub = l >> 4;
  const int q16 = l & 15;
  const int w   = blockIdx.x * 4 + ((int)threadIdx.x >> 6);
  const int nW  = (int)gridDim.x * 4;
  float lacc = 0.f;

  for (int base = w * 4; base < n; base += nW * 4) {
    const int i = base + sub;     // uniform within 16-lane group
    if (i >= n) continue;
    const int row = list[i];
    const int bi = (int)(keyBest[row] & 0xffffffffull);
    const float4 xv = reinterpret_cast<const float4*>(x)[(size_t)row * 16 + q16];
    const float4 ev = reinterpret_cast<const float4*>(emb)[(size_t)bi * 16 + q16];
    const float da = ev.x - xv.x;
    const float db = ev.y - xv.y;
    const float dc = ev.z - xv.z;
    const float dd = ev.w - xv.w;
    float4 o;
    o.x = xv.x + da; o.y = xv.y + db; o.z = xv.z + dc; o.w = xv.w + dd;
    reinterpret_cast<float4*>(out)[(size_t)row * 16 + q16] = o;
    lacc += da * da + db * db + dc * dc + dd * dd;
    if (q16 == 0) out[(size_t)NROWS * DDIM + row] = (float)bi;
  }
  #pragma unroll
  for (int off = 32; off > 0; off >>= 1) lacc += __shfl_down(lacc, off, 64);
  if (l == 0 && lacc != 0.f) atomicAdd(loss_accum, (double)lacc);
}

// ---------------- scalars
__global__ void vq_scalars(const double* __restrict__ loss_accum,
                           float* __restrict__ out) {
  if (threadIdx.x == 0 && blockIdx.x == 0) {
    const double mm = *loss_accum / (double)((size_t)NROWS * DDIM);
    const float el = (float)mm;
    float* tail = out + (size_t)NROWS * DDIM + NROWS;
    tail[0] = 0.25f * el;
    tail[1] = el;
    tail[2] = 0.0f;
  }
}

// ============================================================================
extern "C" void kernel_launch(void* const* d_in, const int* in_sizes, int n_in,
                              void* d_out, int out_size, void* d_ws, size_t ws_size,
                              hipStream_t stream) {
  const float* x   = (const float*)d_in[0];  // [N, 64]
  const float* emb = (const float*)d_in[1];  // [K, 64]
  float* out = (float*)d_out;
  char* ws = (char*)d_ws;

  double* loss_accum = (double*)(ws + WS_LOSS);
  int*    cnt        = (int*)(ws + WS_CNT);
  float*  se         = (float*)(ws + WS_SE);
  short*  ehB        = (short*)(ws + WS_EHB);
  short*  elB        = (short*)(ws + WS_ELB);
  int*    list       = (int*)(ws + WS_LIST);
  unsigned long long* keyBest = (unsigned long long*)(ws + WS_KEY);
  float2* mv         = (float2*)(ws + WS_MV);
  unsigned long long* kv = (unsigned long long*)(ws + WS_KV);

  vq_prep<<<NROWS / 256, 256, 0, stream>>>(emb, se, ehB, elB, keyBest,
                                           loss_accum, cnt);
  vq_fused<<<(NROWS / 128) * 4, 256, 0, stream>>>(x, ehB, elB, se, mv, kv);
  vq_combine_out<<<NROWS / 256, 256, 0, stream>>>(mv, kv, x, emb, list, cnt,
                                                  out, loss_accum);
  vq_exact<<<2048, 64, 0, stream>>>(x, emb, se, list, cnt, keyBest);
  vq_minifinal<<<256, 256, 0, stream>>>(x, emb, list, cnt, keyBest, out,
                                        loss_accum);
  vq_scalars<<<1, 64, 0, stream>>>(loss_accum, out);
}